// Round 10
// baseline (166.664 us; speedup 1.0000x reference)
//
#include <hip/hip_runtime.h>
#include <hip/hip_bf16.h>

typedef __bf16 bf16_t;
typedef __bf16 bf16x8 __attribute__((ext_vector_type(8)));
typedef float  f32x2  __attribute__((ext_vector_type(2)));
typedef float  f32x4  __attribute__((ext_vector_type(4)));
typedef float  f32x16 __attribute__((ext_vector_type(16)));

#define B_ 8
#define C_ 256
#define L_ 4096
#define M_ 2048
#define INV_SQRT2f 0.70710678118654752440f

typedef __attribute__((address_space(3))) void as3_void;
typedef __attribute__((address_space(1))) const void as1_cvoid;

__device__ __forceinline__ void gload_lds16(const void* g, void* l) {
    __builtin_amdgcn_global_load_lds((as1_cvoid*)g, (as3_void*)l, 16, 0, 0);
}

__device__ __forceinline__ unsigned packbf(float a, float b) {
    unsigned short ua = __builtin_bit_cast(unsigned short, (bf16_t)a);
    unsigned short ub = __builtin_bit_cast(unsigned short, (bf16_t)b);
    return (unsigned)ua | ((unsigned)ub << 16);
}

// v_permlane32_swap_b32 — ONLY on operands with DISTINCT values (identical
// values coalesce into one register -> self-swap; round-8 bug).
__device__ __forceinline__ void pl32swapu(unsigned &a, unsigned &b) {
    asm("v_permlane32_swap_b32 %0, %1" : "+v"(a), "+v"(b));
}

// load 8 consecutive f32, convert to bf16x8 (RNE via cast)
__device__ __forceinline__ bf16x8 cvt8(const float* p) {
    f32x4 a = *reinterpret_cast<const f32x4*>(p);
    f32x4 b = *reinterpret_cast<const f32x4*>(p + 4);
    union { unsigned u[4]; bf16x8 v; } w;
    w.u[0] = packbf(a[0], a[1]);
    w.u[1] = packbf(a[2], a[3]);
    w.u[2] = packbf(b[0], b[1]);
    w.u[3] = packbf(b[2], b[3]);
    return w.v;
}

// ================= kernel A: fused Haar + K-proj + V-proj =================
// 512 blocks (b, 32-m-tile) x 256 thr -> 2 blocks/CU, 2 waves/SIMD.
// K and V projections share one ks-loop and one xh LDS read per step.
__global__ __launch_bounds__(256, 2) void kv_proj_kernel(
    const float* __restrict__ x, const float* __restrict__ Wk, const float* __restrict__ bk,
    const float* __restrict__ Wv, const float* __restrict__ bv,
    bf16_t* __restrict__ kb, bf16_t* __restrict__ vb) {
    __shared__ __align__(16) char smem[16384 + 17152];
    char* xh = smem;                           // [32][512B] swizzled bf16
    float* tile = (float*)(smem + 16384);      // f32 [64][67] (odd stride: ~2-way banks)

    const int t = threadIdx.x;
    const int wave = t >> 6, lane = t & 63;
    const int l31 = lane & 31, hi = lane >> 5;
    const int bid = blockIdx.x;
    const int b = bid & 7;
    const int mt = bid >> 3;        // 0..63
    const int m0 = mt * 32;

    // ---- phase 1: build xh (4 c-chunks of 64) ----
    const int c2 = (t & 31) * 2;    // c-pair base within chunk
    const int mg = t >> 5;          // 0..7
    for (int cc = 0; cc < 4; ++cc) {
        if (cc) __syncthreads();
        const float* xs = x + ((size_t)(b * C_ + cc * 64) * L_) + 2 * m0;
#pragma unroll
        for (int j = 0; j < 8; ++j) {
            int row = (t >> 5) * 8 + j;
            f32x2 v = *reinterpret_cast<const f32x2*>(xs + (size_t)row * L_ + (t & 31) * 2);
            tile[row * 67 + (t & 31) * 2]     = v[0];
            tile[row * 67 + (t & 31) * 2 + 1] = v[1];
        }
        __syncthreads();
#pragma unroll
        for (int i = 0; i < 4; ++i) {
            int m = mg * 4 + i;     // 0..31
            float pa0 = tile[c2 * 67 + 2 * m];
            float pa1 = tile[c2 * 67 + 2 * m + 1];
            float pb0 = tile[(c2 + 1) * 67 + 2 * m];
            float pb1 = tile[(c2 + 1) * 67 + 2 * m + 1];
            float va  = (pa0 - pa1) * INV_SQRT2f;
            float vb2 = (pb0 - pb1) * INV_SQRT2f;
            int byte = m * 512 + ((((cc * 64 + c2) * 2)) ^ ((m & 7) << 4));
            *reinterpret_cast<unsigned*>(xh + byte) = packbf(va, vb2);
        }
    }
    __syncthreads();

    // ---- phase 2: merged K-proj + V-proj (shared xh reads) ----
    const int oq = wave;           // o 64-block per wave
    f32x16 kacc[2], vacc[2];
#pragma unroll
    for (int ob = 0; ob < 2; ++ob) {
        float bko = bk[(oq * 2 + ob) * 32 + l31];
#pragma unroll
        for (int r = 0; r < 16; ++r) { kacc[ob][r] = bko; vacc[ob][r] = 0.f; }
    }
    const int s0 = (l31 & 7) << 4;
#pragma unroll
    for (int ks = 0; ks < 16; ++ks) {
        int cb = (ks * 16 + hi * 8) * 2;
        bf16x8 xv = *reinterpret_cast<const bf16x8*>(xh + l31 * 512 + (cb ^ s0));
#pragma unroll
        for (int ob = 0; ob < 2; ++ob) {
            int o = (oq * 2 + ob) * 32 + l31;
            bf16x8 bw = cvt8(Wk + (size_t)o * C_ + ks * 16 + hi * 8);
            kacc[ob] = __builtin_amdgcn_mfma_f32_32x32x16_bf16(xv, bw, kacc[ob], 0, 0, 0);
            bf16x8 aw = cvt8(Wv + (size_t)o * C_ + ks * 16 + hi * 8);
            vacc[ob] = __builtin_amdgcn_mfma_f32_32x32x16_bf16(aw, xv, vacc[ob], 0, 0, 0);
        }
    }
    bf16_t* kout = kb + (size_t)b * M_ * C_;
    bf16_t* vout = vb + (size_t)b * C_ * M_;
#pragma unroll
    for (int ob = 0; ob < 2; ++ob) {
        int o = (oq * 2 + ob) * 32 + l31;
#pragma unroll
        for (int r = 0; r < 16; ++r) {
            int mloc = (r & 3) + 8 * (r >> 2) + 4 * hi;
            kout[(size_t)(m0 + mloc) * C_ + o] = (bf16_t)kacc[ob][r];
        }
#pragma unroll
        for (int r = 0; r < 16; ++r) {
            int ov = (oq * 2 + ob) * 32 + (r & 3) + 8 * (r >> 2) + 4 * hi;
            vout[(size_t)ov * M_ + m0 + l31] = (bf16_t)(vacc[ob][r] + bv[ov]);
        }
    }
}

// ================= kernel B: attention with fused Q-projection =================
#define KT 64
#define NT (M_ / KT)   // 32

__global__ __launch_bounds__(512, 1) void attn_kernel(
    const float* __restrict__ Wq, const float* __restrict__ bq,
    const bf16_t* __restrict__ kb, const bf16_t* __restrict__ vb,
    const float* __restrict__ x, const float* __restrict__ gate, float* __restrict__ out) {
    __shared__ __align__(16) char smem[135168];
    char* Kbase_l = smem;
    char* Vbase_l = smem + 65536;

    const int t = threadIdx.x;
    const int wave = t >> 6, lane = t & 63;
    const int qg = wave & 3, mh = wave >> 2;
    const int l31 = lane & 31, hi = lane >> 5;
    const int bid = blockIdx.x;
    const int b = bid & 7;          // batch -> XCD affinity
    const int lt = bid >> 3;        // 0..31
    const int l0w = lt * 128 + qg * 32;

    bf16x8 qf[16];

    // ======== Q-projection prologue (scale 1/sqrt(C)=2^-4 folded into q) ========
    {
        float* tile = (float*)Vbase_l;   // f32 [64][131] (odd stride)
        char* xt = Kbase_l;              // [128][512B] bf16 swizzled
        const int cp2 = (t & 31) * 2;
        const int lg = t >> 5;           // 0..15
        for (int cc = 0; cc < 4; ++cc) {
            if (cc) __syncthreads();
            const float* xs = x + ((size_t)(b * C_ + cc * 64) * L_) + lt * 128;
#pragma unroll
            for (int j = 0; j < 8; ++j) {
                int e = t + j * 512;
                int row = e >> 6, cp = e & 63;
                f32x2 v = *reinterpret_cast<const f32x2*>(xs + (size_t)row * L_ + cp * 2);
                tile[row * 131 + cp * 2]     = v[0];
                tile[row * 131 + cp * 2 + 1] = v[1];
            }
            __syncthreads();
#pragma unroll
            for (int i = 0; i < 8; ++i) {
                int l = lg * 8 + i;
                float va  = tile[cp2 * 131 + l];
                float vb2 = tile[(cp2 + 1) * 131 + l];
                int byte = l * 512 + ((((cc * 64 + cp2) * 2)) ^ ((l & 7) << 4));
                *reinterpret_cast<unsigned*>(xt + byte) = packbf(va, vb2);
            }
        }
        __syncthreads();

        const int ow = wave * 32;
        f32x16 qacc[4];
#pragma unroll
        for (int lb = 0; lb < 4; ++lb)
#pragma unroll
            for (int r = 0; r < 16; ++r) qacc[lb][r] = 0.f;
#pragma unroll
        for (int ks = 0; ks < 16; ++ks) {
            bf16x8 aw = cvt8(Wq + (size_t)(ow + l31) * C_ + ks * 16 + hi * 8);
#pragma unroll
            for (int lb = 0; lb < 4; ++lb) {
                int lrow = lb * 32 + l31;
                bf16x8 bx = *reinterpret_cast<const bf16x8*>(
                    xt + lrow * 512 + (((ks * 16 + hi * 8) * 2) ^ ((lrow & 7) << 4)));
                qacc[lb] = __builtin_amdgcn_mfma_f32_32x32x16_bf16(aw, bx, qacc[lb], 0, 0, 0);
            }
        }
        __syncthreads();   // xt reads & tile use done; V-space becomes qt
        char* qt = Vbase_l;  // [128][512B] bf16 swizzled, holds q*2^-4
#pragma unroll
        for (int lb = 0; lb < 4; ++lb) {
            int l = lb * 32 + l31;
            int lsw = (l & 7) << 4;
#pragma unroll
            for (int q = 0; q < 4; ++q) {
                int o = ow + 4 * hi + 8 * q;
                f32x4 bq4 = *reinterpret_cast<const f32x4*>(bq + o);
                unsigned w0 = packbf((qacc[lb][q * 4 + 0] + bq4[0]) * 0.0625f,
                                     (qacc[lb][q * 4 + 1] + bq4[1]) * 0.0625f);
                unsigned w1 = packbf((qacc[lb][q * 4 + 2] + bq4[2]) * 0.0625f,
                                     (qacc[lb][q * 4 + 3] + bq4[3]) * 0.0625f);
                unsigned long long w = (unsigned long long)w0 | ((unsigned long long)w1 << 32);
                *reinterpret_cast<unsigned long long*>(qt + l * 512 + ((o * 2) ^ lsw)) = w;
            }
        }
        __syncthreads();
        const int qrow = qg * 32 + l31;
        const int qswz = (qrow & 7) << 4;
#pragma unroll
        for (int ks = 0; ks < 16; ++ks)
            qf[ks] = *reinterpret_cast<const bf16x8*>(
                qt + qrow * 512 + (((ks * 16 + hi * 8) * 2) ^ qswz));
        __syncthreads();   // qf read everywhere; K/V DMA may now overwrite
    }

    // ======== main flash loop ========
    const char* Kg = (const char*)(kb + (size_t)b * M_ * C_);
    const char* Vg = (const char*)(vb + (size_t)b * C_ * M_);
    int ksrc[4], vsrc[4];
#pragma unroll
    for (int i = 0; i < 4; ++i) {
        int chunk = i * 8 + wave;
        int mr = chunk * 2 + (lane >> 5);
        ksrc[i] = mr * 512 + (((lane & 31) * 16) ^ ((mr & 7) << 4));
        int c = chunk * 8 + (lane >> 3);
        vsrc[i] = c * (M_ * 2) + (((lane & 7) * 16) ^ ((c & 7) << 4));
    }

#pragma unroll
    for (int i = 0; i < 4; ++i)
        gload_lds16(Kg + ksrc[i], Kbase_l + (i * 8 + wave) * 1024);
#pragma unroll
    for (int i = 0; i < 4; ++i)
        gload_lds16(Vg + vsrc[i], Vbase_l + (i * 8 + wave) * 1024);

    f32x16 acc[8];
#pragma unroll
    for (int cb = 0; cb < 8; ++cb)
#pragma unroll
        for (int r = 0; r < 16; ++r) acc[cb][r] = 0.f;
    float m_run = -INFINITY, l_run = 0.f;

    asm volatile("s_waitcnt vmcnt(0)" ::: "memory");
    __builtin_amdgcn_s_barrier();
    asm volatile("" ::: "memory");

    for (int kt = 0; kt < NT; ++kt) {
        const int cur = kt & 1;
        if (kt + 1 < NT) {
            const char* Kn = Kg + (size_t)(kt + 1) * 32768;
            char* Kd = Kbase_l + (cur ^ 1) * 32768;
#pragma unroll
            for (int i = 0; i < 4; ++i)
                gload_lds16(Kn + ksrc[i], Kd + (i * 8 + wave) * 1024);
            const char* Vn = Vg + (size_t)(kt + 1) * 128;
            char* Vd = Vbase_l + (cur ^ 1) * 32768;
#pragma unroll
            for (int i = 0; i < 4; ++i)
                gload_lds16(Vn + vsrc[i], Vd + (i * 8 + wave) * 1024);
        }

        // ---- S = K' x Q : two independent even/odd MFMA chains ----
        const char* Kc = Kbase_l + cur * 32768;
        const int mrow = mh * 32 + l31;
        const int msw = (mrow & 7) << 4;
        const int moff = mrow * 512;
        f32x16 se, so;
#pragma unroll
        for (int r = 0; r < 16; ++r) { se[r] = 0.f; so[r] = 0.f; }
        __builtin_amdgcn_s_setprio(1);
#pragma unroll
        for (int ks = 0; ks < 16; ks += 2) {
            int cbe = ks * 32 + hi * 16;
            bf16x8 ae = *reinterpret_cast<const bf16x8*>(Kc + moff + (cbe ^ msw));
            se = __builtin_amdgcn_mfma_f32_32x32x16_bf16(ae, qf[ks], se, 0, 0, 0);
            int cbo = (ks + 1) * 32 + hi * 16;
            bf16x8 ao = *reinterpret_cast<const bf16x8*>(Kc + moff + (cbo ^ msw));
            so = __builtin_amdgcn_mfma_f32_32x32x16_bf16(ao, qf[ks + 1], so, 0, 0, 0);
        }
        __builtin_amdgcn_s_setprio(0);

        // ---- online softmax over this m-half (scale already in q) ----
        float pv[16];
        float tm = -INFINITY;
#pragma unroll
        for (int r = 0; r < 16; ++r) {
            pv[r] = se[r] + so[r];
            tm = fmaxf(tm, pv[r]);
        }
        tm = fmaxf(tm, __shfl_xor(tm, 32));
        if (!__all(tm - m_run <= 8.0f)) {
            float m_new = fmaxf(m_run, tm);
            float corr = __expf(m_run - m_new);
#pragma unroll
            for (int cb = 0; cb < 8; ++cb)
#pragma unroll
                for (int r = 0; r < 16; ++r) acc[cb][r] *= corr;
            l_run *= corr;
            m_run = m_new;
        }
        float rs = 0.f;
#pragma unroll
        for (int i = 0; i < 16; ++i) { pv[i] = __expf(pv[i] - m_run); rs += pv[i]; }
        l_run += rs + __shfl_xor(rs, 32);

        // ---- build P B-frags: 4 permlane swaps (distinct operands) ----
        union PW { unsigned u[4]; bf16x8 v; };
        bf16x8 pfrag[2];
        {
            unsigned Ce0 = packbf(pv[0], pv[1]);
            unsigned Ce1 = packbf(pv[2], pv[3]);
            unsigned Ce2 = packbf(pv[4], pv[5]);
            unsigned Ce3 = packbf(pv[6], pv[7]);
            unsigned Co0 = packbf(pv[8], pv[9]);
            unsigned Co1 = packbf(pv[10], pv[11]);
            unsigned Co2 = packbf(pv[12], pv[13]);
            unsigned Co3 = packbf(pv[14], pv[15]);
            pl32swapu(Ce0, Ce2);
            pl32swapu(Ce1, Ce3);
            pl32swapu(Co0, Co2);
            pl32swapu(Co1, Co3);
            PW we, wo;
            we.u[0] = Ce0; we.u[1] = Ce1; we.u[2] = Ce2; we.u[3] = Ce3;
            wo.u[0] = Co0; wo.u[1] = Co1; wo.u[2] = Co2; wo.u[3] = Co3;
            pfrag[0] = we.v;
            pfrag[1] = wo.v;
        }

        const char* Vc = Vbase_l + cur * 32768;
        __builtin_amdgcn_s_setprio(1);
#pragma unroll
        for (int ks2 = 0; ks2 < 2; ++ks2) {
            int cb2 = (mh * 2 + ks2) * 32 + hi * 16;
#pragma unroll
            for (int cb = 0; cb < 8; ++cb) {
                int c = cb * 32 + l31;
                bf16x8 a = *reinterpret_cast<const bf16x8*>(Vc + c * 128 + (cb2 ^ ((c & 7) << 4)));
                acc[cb] = __builtin_amdgcn_mfma_f32_32x32x16_bf16(a, pfrag[ks2], acc[cb], 0, 0, 0);
            }
        }
        __builtin_amdgcn_s_setprio(0);

        asm volatile("s_waitcnt vmcnt(0)" ::: "memory");
        __builtin_amdgcn_s_barrier();
        asm volatile("" ::: "memory");
    }

    // ---- split-K merge between wave pairs (qg, 0) <-> (qg, 1) ----
    f32x2* mlb = (f32x2*)(smem + 131072);
    f32x2 myml; myml[0] = m_run; myml[1] = l_run;
    mlb[wave * 64 + lane] = myml;
    __syncthreads();
    f32x2 pml = mlb[(wave ^ 4) * 64 + lane];
    float m_star = fmaxf(m_run, pml[0]);
    float f_self = __expf(m_run - m_star);
    float f_peer = __expf(pml[0] - m_star);
    float l_tot = l_run * f_self + pml[1] * f_peer;
#pragma unroll
    for (int cb = 0; cb < 8; ++cb)
#pragma unroll
        for (int r = 0; r < 16; ++r) acc[cb][r] *= f_self;

    char* xbuf = smem;
    const int myoff = (qg * 2 + mh) * 16384;
    __syncthreads();
#pragma unroll
    for (int cbl = 0; cbl < 4; ++cbl)
#pragma unroll
        for (int q = 0; q < 4; ++q) {
            f32x4 chunk;
#pragma unroll
            for (int j = 0; j < 4; ++j) {
                float a_lo = acc[cbl][q * 4 + j];
                float a_hi = acc[4 + cbl][q * 4 + j];
                chunk[j] = mh ? a_lo : a_hi;
            }
            *reinterpret_cast<f32x4*>(xbuf + myoff + (cbl * 4 + q) * 1024 + lane * 16) = chunk;
        }
    __syncthreads();

    const int poff = (qg * 2 + (1 - mh)) * 16384;
    float gt = tanhf(gate[0]);
    float scale = gt / l_tot;
    const float* xp = x + (size_t)b * C_ * L_;
    float* op = out + (size_t)b * C_ * L_;
    int lcol = l0w + l31;
    const int cbase = mh * 4;
#pragma unroll
    for (int cbl = 0; cbl < 4; ++cbl) {
#pragma unroll
        for (int q = 0; q < 4; ++q) {
            f32x4 pc = *reinterpret_cast<const f32x4*>(xbuf + poff + (cbl * 4 + q) * 1024 + lane * 16);
#pragma unroll
            for (int j = 0; j < 4; ++j) {
                float a_lo = acc[cbl][q * 4 + j];
                float a_hi = acc[4 + cbl][q * 4 + j];
                float mine = mh ? a_hi : a_lo;
                int c = (cbase + cbl) * 32 + j + 8 * q + 4 * hi;
                size_t idx = (size_t)c * L_ + lcol;
                op[idx] = (mine + pc[j]) * scale + xp[idx];
            }
        }
    }
}

extern "C" void kernel_launch(void* const* d_in, const int* in_sizes, int n_in,
                              void* d_out, int out_size, void* d_ws, size_t ws_size,
                              hipStream_t stream) {
    const float* x    = (const float*)d_in[0];
    const float* Wq   = (const float*)d_in[1];
    const float* bq   = (const float*)d_in[2];
    const float* Wk   = (const float*)d_in[3];
    const float* bk   = (const float*)d_in[4];
    const float* Wv   = (const float*)d_in[5];
    const float* bv   = (const float*)d_in[6];
    const float* gate = (const float*)d_in[7];
    float* out = (float*)d_out;

    char* ws = (char*)d_ws;
    const size_t szKV = (size_t)B_ * M_ * C_ * 2;   // 8388608
    bf16_t* kbuf = (bf16_t*)(ws);
    bf16_t* vbuf = (bf16_t*)(ws + szKV);

    kv_proj_kernel<<<512, 256, 0, stream>>>(x, Wk, bk, Wv, bv, kbuf, vbuf);
    attn_kernel<<<256, 512, 0, stream>>>(Wq, bq, kbuf, vbuf, x, gate, out);
}

// Round 11
// 142.463 us; speedup vs baseline: 1.1699x; 1.1699x over previous
//
#include <hip/hip_runtime.h>
#include <hip/hip_bf16.h>

typedef __bf16 bf16_t;
typedef __bf16 bf16x8 __attribute__((ext_vector_type(8)));
typedef float  f32x2  __attribute__((ext_vector_type(2)));
typedef float  f32x4  __attribute__((ext_vector_type(4)));
typedef float  f32x16 __attribute__((ext_vector_type(16)));

#define B_ 8
#define C_ 256
#define L_ 4096
#define M_ 2048
#define INV_SQRT2f 0.70710678118654752440f

typedef __attribute__((address_space(3))) void as3_void;
typedef __attribute__((address_space(1))) const void as1_cvoid;

__device__ __forceinline__ void gload_lds16(const void* g, void* l) {
    __builtin_amdgcn_global_load_lds((as1_cvoid*)g, (as3_void*)l, 16, 0, 0);
}

__device__ __forceinline__ unsigned packbf(float a, float b) {
    unsigned short ua = __builtin_bit_cast(unsigned short, (bf16_t)a);
    unsigned short ub = __builtin_bit_cast(unsigned short, (bf16_t)b);
    return (unsigned)ua | ((unsigned)ub << 16);
}

// v_permlane32_swap_b32 — ONLY on operands with DISTINCT values (identical
// values coalesce into one register -> self-swap; round-8 bug).
__device__ __forceinline__ void pl32swapu(unsigned &a, unsigned &b) {
    asm("v_permlane32_swap_b32 %0, %1" : "+v"(a), "+v"(b));
}

// load 8 consecutive f32, convert to bf16x8 (RNE via cast)
__device__ __forceinline__ bf16x8 cvt8(const float* p) {
    f32x4 a = *reinterpret_cast<const f32x4*>(p);
    f32x4 b = *reinterpret_cast<const f32x4*>(p + 4);
    union { unsigned u[4]; bf16x8 v; } w;
    w.u[0] = packbf(a[0], a[1]);
    w.u[1] = packbf(a[2], a[3]);
    w.u[2] = packbf(b[0], b[1]);
    w.u[3] = packbf(b[2], b[3]);
    return w.v;
}

// ================= kernel A: fused Haar + K-proj + V-proj =================
// 512 blocks (b, 32-m-tile) x 256 thr -> 2 blocks/CU, 2 waves/SIMD.
// K and V projections share one ks-loop and one xh LDS read per step.
__global__ __launch_bounds__(256, 2) void kv_proj_kernel(
    const float* __restrict__ x, const float* __restrict__ Wk, const float* __restrict__ bk,
    const float* __restrict__ Wv, const float* __restrict__ bv,
    bf16_t* __restrict__ kb, bf16_t* __restrict__ vb) {
    __shared__ __align__(16) char smem[16384 + 17152];
    char* xh = smem;                           // [32][512B] swizzled bf16
    float* tile = (float*)(smem + 16384);      // f32 [64][67] (odd stride: ~2-way banks)

    const int t = threadIdx.x;
    const int wave = t >> 6, lane = t & 63;
    const int l31 = lane & 31, hi = lane >> 5;
    const int bid = blockIdx.x;
    const int b = bid & 7;
    const int mt = bid >> 3;        // 0..63
    const int m0 = mt * 32;

    // ---- phase 1: build xh (4 c-chunks of 64) ----
    const int c2 = (t & 31) * 2;    // c-pair base within chunk
    const int mg = t >> 5;          // 0..7
    for (int cc = 0; cc < 4; ++cc) {
        if (cc) __syncthreads();
        const float* xs = x + ((size_t)(b * C_ + cc * 64) * L_) + 2 * m0;
#pragma unroll
        for (int j = 0; j < 8; ++j) {
            int row = (t >> 5) * 8 + j;
            f32x2 v = *reinterpret_cast<const f32x2*>(xs + (size_t)row * L_ + (t & 31) * 2);
            tile[row * 67 + (t & 31) * 2]     = v[0];
            tile[row * 67 + (t & 31) * 2 + 1] = v[1];
        }
        __syncthreads();
#pragma unroll
        for (int i = 0; i < 4; ++i) {
            int m = mg * 4 + i;     // 0..31
            float pa0 = tile[c2 * 67 + 2 * m];
            float pa1 = tile[c2 * 67 + 2 * m + 1];
            float pb0 = tile[(c2 + 1) * 67 + 2 * m];
            float pb1 = tile[(c2 + 1) * 67 + 2 * m + 1];
            float va  = (pa0 - pa1) * INV_SQRT2f;
            float vb2 = (pb0 - pb1) * INV_SQRT2f;
            int byte = m * 512 + ((((cc * 64 + c2) * 2)) ^ ((m & 7) << 4));
            *reinterpret_cast<unsigned*>(xh + byte) = packbf(va, vb2);
        }
    }
    __syncthreads();

    // ---- phase 2: merged K-proj + V-proj (shared xh reads) ----
    const int oq = wave;           // o 64-block per wave
    f32x16 kacc[2], vacc[2];
#pragma unroll
    for (int ob = 0; ob < 2; ++ob) {
        float bko = bk[(oq * 2 + ob) * 32 + l31];
#pragma unroll
        for (int r = 0; r < 16; ++r) { kacc[ob][r] = bko; vacc[ob][r] = 0.f; }
    }
    const int s0 = (l31 & 7) << 4;
#pragma unroll
    for (int ks = 0; ks < 16; ++ks) {
        int cb = (ks * 16 + hi * 8) * 2;
        bf16x8 xv = *reinterpret_cast<const bf16x8*>(xh + l31 * 512 + (cb ^ s0));
#pragma unroll
        for (int ob = 0; ob < 2; ++ob) {
            int o = (oq * 2 + ob) * 32 + l31;
            bf16x8 bw = cvt8(Wk + (size_t)o * C_ + ks * 16 + hi * 8);
            kacc[ob] = __builtin_amdgcn_mfma_f32_32x32x16_bf16(xv, bw, kacc[ob], 0, 0, 0);
            bf16x8 aw = cvt8(Wv + (size_t)o * C_ + ks * 16 + hi * 8);
            vacc[ob] = __builtin_amdgcn_mfma_f32_32x32x16_bf16(aw, xv, vacc[ob], 0, 0, 0);
        }
    }
    bf16_t* kout = kb + (size_t)b * M_ * C_;
    bf16_t* vout = vb + (size_t)b * C_ * M_;
#pragma unroll
    for (int ob = 0; ob < 2; ++ob) {
        int o = (oq * 2 + ob) * 32 + l31;
#pragma unroll
        for (int r = 0; r < 16; ++r) {
            int mloc = (r & 3) + 8 * (r >> 2) + 4 * hi;
            kout[(size_t)(m0 + mloc) * C_ + o] = (bf16_t)kacc[ob][r];
        }
#pragma unroll
        for (int r = 0; r < 16; ++r) {
            int ov = (oq * 2 + ob) * 32 + (r & 3) + 8 * (r >> 2) + 4 * hi;
            vout[(size_t)ov * M_ + m0 + l31] = (bf16_t)(vacc[ob][r] + bv[ov]);
        }
    }
}

// ================= kernel B: attention with fused Q-projection =================
#define KT 64
#define NT (M_ / KT)   // 32

__global__ __launch_bounds__(512, 1) void attn_kernel(
    const float* __restrict__ Wq, const float* __restrict__ bq,
    const bf16_t* __restrict__ kb, const bf16_t* __restrict__ vb,
    const float* __restrict__ x, const float* __restrict__ gate, float* __restrict__ out) {
    __shared__ __align__(16) char smem[135168];
    char* Kbase_l = smem;
    char* Vbase_l = smem + 65536;

    const int t = threadIdx.x;
    const int wave = t >> 6, lane = t & 63;
    const int qg = wave & 3, mh = wave >> 2;
    const int l31 = lane & 31, hi = lane >> 5;
    const int bid = blockIdx.x;
    const int b = bid & 7;          // batch -> XCD affinity
    const int lt = bid >> 3;        // 0..31
    const int l0w = lt * 128 + qg * 32;

    bf16x8 qf[16];

    // ======== Q-projection prologue (scale 1/sqrt(C)=2^-4 folded into q) ========
    {
        float* tile = (float*)Vbase_l;   // f32 [64][131] (odd stride)
        char* xt = Kbase_l;              // [128][512B] bf16 swizzled
        const int cp2 = (t & 31) * 2;
        const int lg = t >> 5;           // 0..15
        for (int cc = 0; cc < 4; ++cc) {
            if (cc) __syncthreads();
            const float* xs = x + ((size_t)(b * C_ + cc * 64) * L_) + lt * 128;
#pragma unroll
            for (int j = 0; j < 8; ++j) {
                int e = t + j * 512;
                int row = e >> 6, cp = e & 63;
                f32x2 v = *reinterpret_cast<const f32x2*>(xs + (size_t)row * L_ + cp * 2);
                tile[row * 131 + cp * 2]     = v[0];
                tile[row * 131 + cp * 2 + 1] = v[1];
            }
            __syncthreads();
#pragma unroll
            for (int i = 0; i < 8; ++i) {
                int l = lg * 8 + i;
                float va  = tile[cp2 * 131 + l];
                float vb2 = tile[(cp2 + 1) * 131 + l];
                int byte = l * 512 + ((((cc * 64 + cp2) * 2)) ^ ((l & 7) << 4));
                *reinterpret_cast<unsigned*>(xt + byte) = packbf(va, vb2);
            }
        }
        __syncthreads();

        const int ow = wave * 32;
        f32x16 qacc[4];
#pragma unroll
        for (int lb = 0; lb < 4; ++lb)
#pragma unroll
            for (int r = 0; r < 16; ++r) qacc[lb][r] = 0.f;
#pragma unroll
        for (int ks = 0; ks < 16; ++ks) {
            bf16x8 aw = cvt8(Wq + (size_t)(ow + l31) * C_ + ks * 16 + hi * 8);
#pragma unroll
            for (int lb = 0; lb < 4; ++lb) {
                int lrow = lb * 32 + l31;
                bf16x8 bx = *reinterpret_cast<const bf16x8*>(
                    xt + lrow * 512 + (((ks * 16 + hi * 8) * 2) ^ ((lrow & 7) << 4)));
                qacc[lb] = __builtin_amdgcn_mfma_f32_32x32x16_bf16(aw, bx, qacc[lb], 0, 0, 0);
            }
        }
        __syncthreads();   // xt reads & tile use done; V-space becomes qt
        char* qt = Vbase_l;  // [128][512B] bf16 swizzled, holds q*2^-4
#pragma unroll
        for (int lb = 0; lb < 4; ++lb) {
            int l = lb * 32 + l31;
            int lsw = (l & 7) << 4;
#pragma unroll
            for (int q = 0; q < 4; ++q) {
                int o = ow + 4 * hi + 8 * q;
                f32x4 bq4 = *reinterpret_cast<const f32x4*>(bq + o);
                unsigned w0 = packbf((qacc[lb][q * 4 + 0] + bq4[0]) * 0.0625f,
                                     (qacc[lb][q * 4 + 1] + bq4[1]) * 0.0625f);
                unsigned w1 = packbf((qacc[lb][q * 4 + 2] + bq4[2]) * 0.0625f,
                                     (qacc[lb][q * 4 + 3] + bq4[3]) * 0.0625f);
                unsigned long long w = (unsigned long long)w0 | ((unsigned long long)w1 << 32);
                *reinterpret_cast<unsigned long long*>(qt + l * 512 + ((o * 2) ^ lsw)) = w;
            }
        }
        __syncthreads();
        const int qrow = qg * 32 + l31;
        const int qswz = (qrow & 7) << 4;
#pragma unroll
        for (int ks = 0; ks < 16; ++ks)
            qf[ks] = *reinterpret_cast<const bf16x8*>(
                qt + qrow * 512 + (((ks * 16 + hi * 8) * 2) ^ qswz));
        __syncthreads();   // qf read everywhere; K/V DMA may now overwrite
    }

    // ======== main flash loop (round-9 verified form) ========
    const char* Kg = (const char*)(kb + (size_t)b * M_ * C_);
    const char* Vg = (const char*)(vb + (size_t)b * C_ * M_);
    int ksrc[4], vsrc[4];
#pragma unroll
    for (int i = 0; i < 4; ++i) {
        int chunk = i * 8 + wave;
        int mr = chunk * 2 + (lane >> 5);
        ksrc[i] = mr * 512 + (((lane & 31) * 16) ^ ((mr & 7) << 4));
        int c = chunk * 8 + (lane >> 3);
        vsrc[i] = c * (M_ * 2) + (((lane & 7) * 16) ^ ((c & 7) << 4));
    }

#pragma unroll
    for (int i = 0; i < 4; ++i)
        gload_lds16(Kg + ksrc[i], Kbase_l + (i * 8 + wave) * 1024);
#pragma unroll
    for (int i = 0; i < 4; ++i)
        gload_lds16(Vg + vsrc[i], Vbase_l + (i * 8 + wave) * 1024);

    f32x16 acc[8];
#pragma unroll
    for (int cb = 0; cb < 8; ++cb)
#pragma unroll
        for (int r = 0; r < 16; ++r) acc[cb][r] = 0.f;
    float m_run = -INFINITY, l_run = 0.f;

    asm volatile("s_waitcnt vmcnt(0)" ::: "memory");
    __builtin_amdgcn_s_barrier();
    asm volatile("" ::: "memory");

    for (int kt = 0; kt < NT; ++kt) {
        const int cur = kt & 1;
        if (kt + 1 < NT) {
            const char* Kn = Kg + (size_t)(kt + 1) * 32768;
            char* Kd = Kbase_l + (cur ^ 1) * 32768;
#pragma unroll
            for (int i = 0; i < 4; ++i)
                gload_lds16(Kn + ksrc[i], Kd + (i * 8 + wave) * 1024);
            const char* Vn = Vg + (size_t)(kt + 1) * 128;
            char* Vd = Vbase_l + (cur ^ 1) * 32768;
#pragma unroll
            for (int i = 0; i < 4; ++i)
                gload_lds16(Vn + vsrc[i], Vd + (i * 8 + wave) * 1024);
        }

        // ---- S = K' x Q : single accumulator chain (register budget!) ----
        // (round-10's even/odd split added +16 acc regs -> unified-file spill)
        const char* Kc = Kbase_l + cur * 32768;
        const int mrow = mh * 32 + l31;
        const int msw = (mrow & 7) << 4;
        const int moff = mrow * 512;
        f32x16 s;
#pragma unroll
        for (int r = 0; r < 16; ++r) s[r] = 0.f;
        __builtin_amdgcn_s_setprio(1);
#pragma unroll
        for (int ks = 0; ks < 16; ++ks) {
            int cb2 = ks * 32 + hi * 16;
            bf16x8 a = *reinterpret_cast<const bf16x8*>(Kc + moff + (cb2 ^ msw));
            s = __builtin_amdgcn_mfma_f32_32x32x16_bf16(a, qf[ks], s, 0, 0, 0);
        }
        __builtin_amdgcn_s_setprio(0);

        // ---- online softmax over this m-half (scale already in q) ----
        float pv[16];
        float tm = -INFINITY;
#pragma unroll
        for (int r = 0; r < 16; ++r) {
            pv[r] = s[r];
            tm = fmaxf(tm, s[r]);
        }
        tm = fmaxf(tm, __shfl_xor(tm, 32));
        if (!__all(tm - m_run <= 8.0f)) {
            float m_new = fmaxf(m_run, tm);
            float corr = __expf(m_run - m_new);
#pragma unroll
            for (int cb = 0; cb < 8; ++cb)
#pragma unroll
                for (int r = 0; r < 16; ++r) acc[cb][r] *= corr;
            l_run *= corr;
            m_run = m_new;
        }
        float rs = 0.f;
#pragma unroll
        for (int i = 0; i < 16; ++i) { pv[i] = __expf(pv[i] - m_run); rs += pv[i]; }
        l_run += rs + __shfl_xor(rs, 32);

        // ---- build P B-frags: 4 permlane swaps (distinct operands) ----
        union PW { unsigned u[4]; bf16x8 v; };
        bf16x8 pfrag[2];
        {
            unsigned Ce0 = packbf(pv[0], pv[1]);
            unsigned Ce1 = packbf(pv[2], pv[3]);
            unsigned Ce2 = packbf(pv[4], pv[5]);
            unsigned Ce3 = packbf(pv[6], pv[7]);
            unsigned Co0 = packbf(pv[8], pv[9]);
            unsigned Co1 = packbf(pv[10], pv[11]);
            unsigned Co2 = packbf(pv[12], pv[13]);
            unsigned Co3 = packbf(pv[14], pv[15]);
            pl32swapu(Ce0, Ce2);
            pl32swapu(Ce1, Ce3);
            pl32swapu(Co0, Co2);
            pl32swapu(Co1, Co3);
            PW we, wo;
            we.u[0] = Ce0; we.u[1] = Ce1; we.u[2] = Ce2; we.u[3] = Ce3;
            wo.u[0] = Co0; wo.u[1] = Co1; wo.u[2] = Co2; wo.u[3] = Co3;
            pfrag[0] = we.v;
            pfrag[1] = wo.v;
        }

        const char* Vc = Vbase_l + cur * 32768;
        __builtin_amdgcn_s_setprio(1);
#pragma unroll
        for (int ks2 = 0; ks2 < 2; ++ks2) {
            int cb2 = (mh * 2 + ks2) * 32 + hi * 16;
#pragma unroll
            for (int cb = 0; cb < 8; ++cb) {
                int c = cb * 32 + l31;
                bf16x8 a = *reinterpret_cast<const bf16x8*>(Vc + c * 128 + (cb2 ^ ((c & 7) << 4)));
                acc[cb] = __builtin_amdgcn_mfma_f32_32x32x16_bf16(a, pfrag[ks2], acc[cb], 0, 0, 0);
            }
        }
        __builtin_amdgcn_s_setprio(0);

        asm volatile("s_waitcnt vmcnt(0)" ::: "memory");
        __builtin_amdgcn_s_barrier();
        asm volatile("" ::: "memory");
    }

    // ---- split-K merge between wave pairs (qg, 0) <-> (qg, 1) ----
    f32x2* mlb = (f32x2*)(smem + 131072);
    f32x2 myml; myml[0] = m_run; myml[1] = l_run;
    mlb[wave * 64 + lane] = myml;
    __syncthreads();
    f32x2 pml = mlb[(wave ^ 4) * 64 + lane];
    float m_star = fmaxf(m_run, pml[0]);
    float f_self = __expf(m_run - m_star);
    float f_peer = __expf(pml[0] - m_star);
    float l_tot = l_run * f_self + pml[1] * f_peer;
#pragma unroll
    for (int cb = 0; cb < 8; ++cb)
#pragma unroll
        for (int r = 0; r < 16; ++r) acc[cb][r] *= f_self;

    char* xbuf = smem;
    const int myoff = (qg * 2 + mh) * 16384;
    __syncthreads();
#pragma unroll
    for (int cbl = 0; cbl < 4; ++cbl)
#pragma unroll
        for (int q = 0; q < 4; ++q) {
            f32x4 chunk;
#pragma unroll
            for (int j = 0; j < 4; ++j) {
                float a_lo = acc[cbl][q * 4 + j];
                float a_hi = acc[4 + cbl][q * 4 + j];
                chunk[j] = mh ? a_lo : a_hi;
            }
            *reinterpret_cast<f32x4*>(xbuf + myoff + (cbl * 4 + q) * 1024 + lane * 16) = chunk;
        }
    __syncthreads();

    const int poff = (qg * 2 + (1 - mh)) * 16384;
    float gt = tanhf(gate[0]);
    float scale = gt / l_tot;
    const float* xp = x + (size_t)b * C_ * L_;
    float* op = out + (size_t)b * C_ * L_;
    int lcol = l0w + l31;
    const int cbase = mh * 4;
#pragma unroll
    for (int cbl = 0; cbl < 4; ++cbl) {
#pragma unroll
        for (int q = 0; q < 4; ++q) {
            f32x4 pc = *reinterpret_cast<const f32x4*>(xbuf + poff + (cbl * 4 + q) * 1024 + lane * 16);
#pragma unroll
            for (int j = 0; j < 4; ++j) {
                float a_lo = acc[cbl][q * 4 + j];
                float a_hi = acc[4 + cbl][q * 4 + j];
                float mine = mh ? a_hi : a_lo;
                int c = (cbase + cbl) * 32 + j + 8 * q + 4 * hi;
                size_t idx = (size_t)c * L_ + lcol;
                op[idx] = (mine + pc[j]) * scale + xp[idx];
            }
        }
    }
}

extern "C" void kernel_launch(void* const* d_in, const int* in_sizes, int n_in,
                              void* d_out, int out_size, void* d_ws, size_t ws_size,
                              hipStream_t stream) {
    const float* x    = (const float*)d_in[0];
    const float* Wq   = (const float*)d_in[1];
    const float* bq   = (const float*)d_in[2];
    const float* Wk   = (const float*)d_in[3];
    const float* bk   = (const float*)d_in[4];
    const float* Wv   = (const float*)d_in[5];
    const float* bv   = (const float*)d_in[6];
    const float* gate = (const float*)d_in[7];
    float* out = (float*)d_out;

    char* ws = (char*)d_ws;
    const size_t szKV = (size_t)B_ * M_ * C_ * 2;   // 8388608
    bf16_t* kbuf = (bf16_t*)(ws);
    bf16_t* vbuf = (bf16_t*)(ws + szKV);

    kv_proj_kernel<<<512, 256, 0, stream>>>(x, Wk, bk, Wv, bv, kbuf, vbuf);
    attn_kernel<<<256, 512, 0, stream>>>(Wq, bq, kbuf, vbuf, x, gate, out);
}

// Round 12
// 125.497 us; speedup vs baseline: 1.3280x; 1.1352x over previous
//
#include <hip/hip_runtime.h>
#include <hip/hip_bf16.h>

typedef __bf16 bf16_t;
typedef __bf16 bf16x8 __attribute__((ext_vector_type(8)));
typedef float  f32x2  __attribute__((ext_vector_type(2)));
typedef float  f32x4  __attribute__((ext_vector_type(4)));
typedef float  f32x16 __attribute__((ext_vector_type(16)));

#define B_ 8
#define C_ 256
#define L_ 4096
#define M_ 2048
#define INV_SQRT2f 0.70710678118654752440f

typedef __attribute__((address_space(3))) void as3_void;
typedef __attribute__((address_space(1))) const void as1_cvoid;

__device__ __forceinline__ void gload_lds16(const void* g, void* l) {
    __builtin_amdgcn_global_load_lds((as1_cvoid*)g, (as3_void*)l, 16, 0, 0);
}

__device__ __forceinline__ const bf16x8* ldg8(const bf16_t* p) {
    return reinterpret_cast<const bf16x8*>(p);
}

__device__ __forceinline__ unsigned packbf(float a, float b) {
    unsigned short ua = __builtin_bit_cast(unsigned short, (bf16_t)a);
    unsigned short ub = __builtin_bit_cast(unsigned short, (bf16_t)b);
    return (unsigned)ua | ((unsigned)ub << 16);
}

// v_permlane32_swap_b32 — ONLY on operands with DISTINCT values (identical
// values coalesce into one register -> self-swap; round-8 bug).
__device__ __forceinline__ void pl32swapu(unsigned &a, unsigned &b) {
    asm("v_permlane32_swap_b32 %0, %1" : "+v"(a), "+v"(b));
}

// ---------------- kernel 0: weight conversion f32 -> bf16 (once) ----------------
__global__ __launch_bounds__(256) void conv_w_kernel(
    const float* __restrict__ Wq, const float* __restrict__ Wk, const float* __restrict__ Wv,
    bf16_t* __restrict__ Wqb, bf16_t* __restrict__ Wkb, bf16_t* __restrict__ Wvb) {
    int idx = blockIdx.x * 256 + threadIdx.x;      // 0..196607
    int which = idx >> 16;
    int off = idx & 65535;
    const float* src = (which == 0) ? Wq : ((which == 1) ? Wk : Wv);
    bf16_t* dst = (which == 0) ? Wqb : ((which == 1) ? Wkb : Wvb);
    dst[off] = (bf16_t)src[off];
}

// ================= kernel A: fused Haar + K-proj + V-proj =================
// 512 blocks (b, 32-m-tile) x 256 thr -> 2 blocks/CU, 2 waves/SIMD.
// K and V projections share one ks-loop and one xh LDS read per step.
__global__ __launch_bounds__(256, 2) void kv_proj_kernel(
    const float* __restrict__ x, const bf16_t* __restrict__ Wk, const float* __restrict__ bk,
    const bf16_t* __restrict__ Wv, const float* __restrict__ bv,
    bf16_t* __restrict__ kb, bf16_t* __restrict__ vb) {
    __shared__ __align__(16) char smem[16384 + 33280];
    char* xh = smem;                           // [32][512B] swizzled bf16
    float* tile = (float*)(smem + 16384);      // f32 [64][130] (f32x2-aligned)

    const int t = threadIdx.x;
    const int wave = t >> 6, lane = t & 63;
    const int l31 = lane & 31, hi = lane >> 5;
    const int bid = blockIdx.x;
    const int b = bid & 7;
    const int mt = bid >> 3;        // 0..63
    const int m0 = mt * 32;

    // ---- phase 1: build xh (4 c-chunks of 64), f32x2 LDS ops ----
    const int c2 = (t & 31) * 2;    // c-pair base within chunk
    const int mg = t >> 5;          // 0..7
    for (int cc = 0; cc < 4; ++cc) {
        if (cc) __syncthreads();
        const float* xs = x + ((size_t)(b * C_ + cc * 64) * L_) + 2 * m0;
#pragma unroll
        for (int j = 0; j < 8; ++j) {
            int e = t + j * 256;
            int row = e >> 5, cp = e & 31;
            f32x2 v = *reinterpret_cast<const f32x2*>(xs + (size_t)row * L_ + cp * 2);
            *reinterpret_cast<f32x2*>(tile + row * 130 + cp * 2) = v;
        }
        __syncthreads();
#pragma unroll
        for (int i = 0; i < 4; ++i) {
            int m = mg * 4 + i;     // 0..31
            f32x2 pa = *reinterpret_cast<const f32x2*>(tile + c2 * 130 + 2 * m);
            f32x2 pb = *reinterpret_cast<const f32x2*>(tile + (c2 + 1) * 130 + 2 * m);
            float va  = (pa[0] - pa[1]) * INV_SQRT2f;
            float vb2 = (pb[0] - pb[1]) * INV_SQRT2f;
            int byte = m * 512 + ((((cc * 64 + c2) * 2)) ^ ((m & 7) << 4));
            *reinterpret_cast<unsigned*>(xh + byte) = packbf(va, vb2);
        }
    }
    __syncthreads();

    // ---- phase 2: merged K-proj + V-proj (shared xh reads, bf16 weights) ----
    const int oq = wave;           // o 64-block per wave
    f32x16 kacc[2], vacc[2];
#pragma unroll
    for (int ob = 0; ob < 2; ++ob) {
        float bko = bk[(oq * 2 + ob) * 32 + l31];
#pragma unroll
        for (int r = 0; r < 16; ++r) { kacc[ob][r] = bko; vacc[ob][r] = 0.f; }
    }
    const int s0 = (l31 & 7) << 4;
#pragma unroll
    for (int ks = 0; ks < 16; ++ks) {
        int cb = (ks * 16 + hi * 8) * 2;
        bf16x8 xv = *reinterpret_cast<const bf16x8*>(xh + l31 * 512 + (cb ^ s0));
#pragma unroll
        for (int ob = 0; ob < 2; ++ob) {
            int o = (oq * 2 + ob) * 32 + l31;
            bf16x8 bw = *ldg8(Wk + (size_t)o * C_ + ks * 16 + hi * 8);
            kacc[ob] = __builtin_amdgcn_mfma_f32_32x32x16_bf16(xv, bw, kacc[ob], 0, 0, 0);
            bf16x8 aw = *ldg8(Wv + (size_t)o * C_ + ks * 16 + hi * 8);
            vacc[ob] = __builtin_amdgcn_mfma_f32_32x32x16_bf16(aw, xv, vacc[ob], 0, 0, 0);
        }
    }
    bf16_t* kout = kb + (size_t)b * M_ * C_;
    bf16_t* vout = vb + (size_t)b * C_ * M_;
#pragma unroll
    for (int ob = 0; ob < 2; ++ob) {
        int o = (oq * 2 + ob) * 32 + l31;
#pragma unroll
        for (int r = 0; r < 16; ++r) {
            int mloc = (r & 3) + 8 * (r >> 2) + 4 * hi;
            kout[(size_t)(m0 + mloc) * C_ + o] = (bf16_t)kacc[ob][r];
        }
#pragma unroll
        for (int r = 0; r < 16; ++r) {
            int ov = (oq * 2 + ob) * 32 + (r & 3) + 8 * (r >> 2) + 4 * hi;
            vout[(size_t)ov * M_ + m0 + l31] = (bf16_t)(vacc[ob][r] + bv[ov]);
        }
    }
}

// ================= kernel B: attention with fused Q-projection =================
#define KT 64
#define NT (M_ / KT)   // 32

__global__ __launch_bounds__(512, 1) void attn_kernel(
    const bf16_t* __restrict__ Wq, const float* __restrict__ bq,
    const bf16_t* __restrict__ kb, const bf16_t* __restrict__ vb,
    const float* __restrict__ x, const float* __restrict__ gate, float* __restrict__ out) {
    __shared__ __align__(16) char smem[135168];
    char* Kbase_l = smem;
    char* Vbase_l = smem + 65536;

    const int t = threadIdx.x;
    const int wave = t >> 6, lane = t & 63;
    const int qg = wave & 3, mh = wave >> 2;
    const int l31 = lane & 31, hi = lane >> 5;
    const int bid = blockIdx.x;
    const int b = bid & 7;          // batch -> XCD affinity
    const int lt = bid >> 3;        // 0..31
    const int l0w = lt * 128 + qg * 32;

    bf16x8 qf[16];

    // ======== Q-projection prologue (scale 1/sqrt(C)=2^-4 folded into q) ========
    {
        float* tile = (float*)Vbase_l;   // f32 [64][130]
        char* xt = Kbase_l;              // [128][512B] bf16 swizzled
        const int cp2 = (t & 31) * 2;
        const int lg = t >> 5;           // 0..15
        for (int cc = 0; cc < 4; ++cc) {
            if (cc) __syncthreads();
            const float* xs = x + ((size_t)(b * C_ + cc * 64) * L_) + lt * 128;
#pragma unroll
            for (int j = 0; j < 8; ++j) {
                int e = t + j * 512;
                int row = e >> 6, cp = e & 63;
                f32x2 v = *reinterpret_cast<const f32x2*>(xs + (size_t)row * L_ + cp * 2);
                *reinterpret_cast<f32x2*>(tile + row * 130 + cp * 2) = v;
            }
            __syncthreads();
#pragma unroll
            for (int i = 0; i < 8; ++i) {
                int l = lg * 8 + i;
                float va  = tile[cp2 * 130 + l];
                float vb2 = tile[(cp2 + 1) * 130 + l];
                int byte = l * 512 + ((((cc * 64 + cp2) * 2)) ^ ((l & 7) << 4));
                *reinterpret_cast<unsigned*>(xt + byte) = packbf(va, vb2);
            }
        }
        __syncthreads();

        const int ow = wave * 32;
        f32x16 qacc[4];
#pragma unroll
        for (int lb = 0; lb < 4; ++lb)
#pragma unroll
            for (int r = 0; r < 16; ++r) qacc[lb][r] = 0.f;
#pragma unroll
        for (int ks = 0; ks < 16; ++ks) {
            bf16x8 aw = *ldg8(Wq + (size_t)(ow + l31) * C_ + ks * 16 + hi * 8);
#pragma unroll
            for (int lb = 0; lb < 4; ++lb) {
                int lrow = lb * 32 + l31;
                bf16x8 bx = *reinterpret_cast<const bf16x8*>(
                    xt + lrow * 512 + (((ks * 16 + hi * 8) * 2) ^ ((lrow & 7) << 4)));
                qacc[lb] = __builtin_amdgcn_mfma_f32_32x32x16_bf16(aw, bx, qacc[lb], 0, 0, 0);
            }
        }
        __syncthreads();   // xt reads & tile use done; V-space becomes qt
        char* qt = Vbase_l;  // [128][512B] bf16 swizzled, holds q*2^-4
#pragma unroll
        for (int lb = 0; lb < 4; ++lb) {
            int l = lb * 32 + l31;
            int lsw = (l & 7) << 4;
#pragma unroll
            for (int q = 0; q < 4; ++q) {
                int o = ow + 4 * hi + 8 * q;
                f32x4 bq4 = *reinterpret_cast<const f32x4*>(bq + o);
                unsigned w0 = packbf((qacc[lb][q * 4 + 0] + bq4[0]) * 0.0625f,
                                     (qacc[lb][q * 4 + 1] + bq4[1]) * 0.0625f);
                unsigned w1 = packbf((qacc[lb][q * 4 + 2] + bq4[2]) * 0.0625f,
                                     (qacc[lb][q * 4 + 3] + bq4[3]) * 0.0625f);
                unsigned long long w = (unsigned long long)w0 | ((unsigned long long)w1 << 32);
                *reinterpret_cast<unsigned long long*>(qt + l * 512 + ((o * 2) ^ lsw)) = w;
            }
        }
        __syncthreads();
        const int qrow = qg * 32 + l31;
        const int qswz = (qrow & 7) << 4;
#pragma unroll
        for (int ks = 0; ks < 16; ++ks)
            qf[ks] = *reinterpret_cast<const bf16x8*>(
                qt + qrow * 512 + (((ks * 16 + hi * 8) * 2) ^ qswz));
        __syncthreads();   // qf read everywhere; K/V DMA may now overwrite
    }

    // ======== main flash loop (round-9 verified form) ========
    const char* Kg = (const char*)(kb + (size_t)b * M_ * C_);
    const char* Vg = (const char*)(vb + (size_t)b * C_ * M_);
    int ksrc[4], vsrc[4];
#pragma unroll
    for (int i = 0; i < 4; ++i) {
        int chunk = i * 8 + wave;
        int mr = chunk * 2 + (lane >> 5);
        ksrc[i] = mr * 512 + (((lane & 31) * 16) ^ ((mr & 7) << 4));
        int c = chunk * 8 + (lane >> 3);
        vsrc[i] = c * (M_ * 2) + (((lane & 7) * 16) ^ ((c & 7) << 4));
    }

#pragma unroll
    for (int i = 0; i < 4; ++i)
        gload_lds16(Kg + ksrc[i], Kbase_l + (i * 8 + wave) * 1024);
#pragma unroll
    for (int i = 0; i < 4; ++i)
        gload_lds16(Vg + vsrc[i], Vbase_l + (i * 8 + wave) * 1024);

    f32x16 acc[8];
#pragma unroll
    for (int cb = 0; cb < 8; ++cb)
#pragma unroll
        for (int r = 0; r < 16; ++r) acc[cb][r] = 0.f;
    float m_run = -INFINITY, l_run = 0.f;

    asm volatile("s_waitcnt vmcnt(0)" ::: "memory");
    __builtin_amdgcn_s_barrier();
    asm volatile("" ::: "memory");

    for (int kt = 0; kt < NT; ++kt) {
        const int cur = kt & 1;
        if (kt + 1 < NT) {
            const char* Kn = Kg + (size_t)(kt + 1) * 32768;
            char* Kd = Kbase_l + (cur ^ 1) * 32768;
#pragma unroll
            for (int i = 0; i < 4; ++i)
                gload_lds16(Kn + ksrc[i], Kd + (i * 8 + wave) * 1024);
            const char* Vn = Vg + (size_t)(kt + 1) * 128;
            char* Vd = Vbase_l + (cur ^ 1) * 32768;
#pragma unroll
            for (int i = 0; i < 4; ++i)
                gload_lds16(Vn + vsrc[i], Vd + (i * 8 + wave) * 1024);
        }

        // ---- S = K' x Q : single accumulator chain (register budget!) ----
        const char* Kc = Kbase_l + cur * 32768;
        const int mrow = mh * 32 + l31;
        const int msw = (mrow & 7) << 4;
        const int moff = mrow * 512;
        f32x16 s;
#pragma unroll
        for (int r = 0; r < 16; ++r) s[r] = 0.f;
        __builtin_amdgcn_s_setprio(1);
#pragma unroll
        for (int ks = 0; ks < 16; ++ks) {
            int cb2 = ks * 32 + hi * 16;
            bf16x8 a = *reinterpret_cast<const bf16x8*>(Kc + moff + (cb2 ^ msw));
            s = __builtin_amdgcn_mfma_f32_32x32x16_bf16(a, qf[ks], s, 0, 0, 0);
        }
        __builtin_amdgcn_s_setprio(0);

        // ---- online softmax over this m-half (scale already in q) ----
        float pv[16];
        float tm = -INFINITY;
#pragma unroll
        for (int r = 0; r < 16; ++r) {
            pv[r] = s[r];
            tm = fmaxf(tm, s[r]);
        }
        tm = fmaxf(tm, __shfl_xor(tm, 32));
        if (!__all(tm - m_run <= 8.0f)) {
            float m_new = fmaxf(m_run, tm);
            float corr = __expf(m_run - m_new);
#pragma unroll
            for (int cb = 0; cb < 8; ++cb)
#pragma unroll
                for (int r = 0; r < 16; ++r) acc[cb][r] *= corr;
            l_run *= corr;
            m_run = m_new;
        }
        float rs = 0.f;
#pragma unroll
        for (int i = 0; i < 16; ++i) { pv[i] = __expf(pv[i] - m_run); rs += pv[i]; }
        l_run += rs + __shfl_xor(rs, 32);

        // ---- build P B-frags: 4 permlane swaps (distinct operands) ----
        union PW { unsigned u[4]; bf16x8 v; };
        bf16x8 pfrag[2];
        {
            unsigned Ce0 = packbf(pv[0], pv[1]);
            unsigned Ce1 = packbf(pv[2], pv[3]);
            unsigned Ce2 = packbf(pv[4], pv[5]);
            unsigned Ce3 = packbf(pv[6], pv[7]);
            unsigned Co0 = packbf(pv[8], pv[9]);
            unsigned Co1 = packbf(pv[10], pv[11]);
            unsigned Co2 = packbf(pv[12], pv[13]);
            unsigned Co3 = packbf(pv[14], pv[15]);
            pl32swapu(Ce0, Ce2);
            pl32swapu(Ce1, Ce3);
            pl32swapu(Co0, Co2);
            pl32swapu(Co1, Co3);
            PW we, wo;
            we.u[0] = Ce0; we.u[1] = Ce1; we.u[2] = Ce2; we.u[3] = Ce3;
            wo.u[0] = Co0; wo.u[1] = Co1; wo.u[2] = Co2; wo.u[3] = Co3;
            pfrag[0] = we.v;
            pfrag[1] = wo.v;
        }

        const char* Vc = Vbase_l + cur * 32768;
        __builtin_amdgcn_s_setprio(1);
#pragma unroll
        for (int ks2 = 0; ks2 < 2; ++ks2) {
            int cb2 = (mh * 2 + ks2) * 32 + hi * 16;
#pragma unroll
            for (int cb = 0; cb < 8; ++cb) {
                int c = cb * 32 + l31;
                bf16x8 a = *reinterpret_cast<const bf16x8*>(Vc + c * 128 + (cb2 ^ ((c & 7) << 4)));
                acc[cb] = __builtin_amdgcn_mfma_f32_32x32x16_bf16(a, pfrag[ks2], acc[cb], 0, 0, 0);
            }
        }
        __builtin_amdgcn_s_setprio(0);

        asm volatile("s_waitcnt vmcnt(0)" ::: "memory");
        __builtin_amdgcn_s_barrier();
        asm volatile("" ::: "memory");
    }

    // ---- split-K merge between wave pairs (qg, 0) <-> (qg, 1) ----
    f32x2* mlb = (f32x2*)(smem + 131072);
    f32x2 myml; myml[0] = m_run; myml[1] = l_run;
    mlb[wave * 64 + lane] = myml;
    __syncthreads();
    f32x2 pml = mlb[(wave ^ 4) * 64 + lane];
    float m_star = fmaxf(m_run, pml[0]);
    float f_self = __expf(m_run - m_star);
    float f_peer = __expf(pml[0] - m_star);
    float l_tot = l_run * f_self + pml[1] * f_peer;
#pragma unroll
    for (int cb = 0; cb < 8; ++cb)
#pragma unroll
        for (int r = 0; r < 16; ++r) acc[cb][r] *= f_self;

    char* xbuf = smem;
    const int myoff = (qg * 2 + mh) * 16384;
    __syncthreads();
#pragma unroll
    for (int cbl = 0; cbl < 4; ++cbl)
#pragma unroll
        for (int q = 0; q < 4; ++q) {
            f32x4 chunk;
#pragma unroll
            for (int j = 0; j < 4; ++j) {
                float a_lo = acc[cbl][q * 4 + j];
                float a_hi = acc[4 + cbl][q * 4 + j];
                chunk[j] = mh ? a_lo : a_hi;
            }
            *reinterpret_cast<f32x4*>(xbuf + myoff + (cbl * 4 + q) * 1024 + lane * 16) = chunk;
        }
    __syncthreads();

    const int poff = (qg * 2 + (1 - mh)) * 16384;
    float gt = tanhf(gate[0]);
    float scale = gt / l_tot;
    const float* xp = x + (size_t)b * C_ * L_;
    float* op = out + (size_t)b * C_ * L_;
    int lcol = l0w + l31;
    const int cbase = mh * 4;
#pragma unroll
    for (int cbl = 0; cbl < 4; ++cbl) {
#pragma unroll
        for (int q = 0; q < 4; ++q) {
            f32x4 pc = *reinterpret_cast<const f32x4*>(xbuf + poff + (cbl * 4 + q) * 1024 + lane * 16);
#pragma unroll
            for (int j = 0; j < 4; ++j) {
                float a_lo = acc[cbl][q * 4 + j];
                float a_hi = acc[4 + cbl][q * 4 + j];
                float mine = mh ? a_hi : a_lo;
                int c = (cbase + cbl) * 32 + j + 8 * q + 4 * hi;
                size_t idx = (size_t)c * L_ + lcol;
                op[idx] = (mine + pc[j]) * scale + xp[idx];
            }
        }
    }
}

extern "C" void kernel_launch(void* const* d_in, const int* in_sizes, int n_in,
                              void* d_out, int out_size, void* d_ws, size_t ws_size,
                              hipStream_t stream) {
    const float* x    = (const float*)d_in[0];
    const float* Wq   = (const float*)d_in[1];
    const float* bq   = (const float*)d_in[2];
    const float* Wk   = (const float*)d_in[3];
    const float* bk   = (const float*)d_in[4];
    const float* Wv   = (const float*)d_in[5];
    const float* bv   = (const float*)d_in[6];
    const float* gate = (const float*)d_in[7];
    float* out = (float*)d_out;

    char* ws = (char*)d_ws;
    const size_t szKV = (size_t)B_ * M_ * C_ * 2;   // 8388608
    const size_t szW  = (size_t)C_ * C_ * 2;        // 131072
    bf16_t* kbuf = (bf16_t*)(ws);
    bf16_t* vbuf = (bf16_t*)(ws + szKV);
    bf16_t* Wqb  = (bf16_t*)(ws + 2 * szKV);
    bf16_t* Wkb  = (bf16_t*)(ws + 2 * szKV + szW);
    bf16_t* Wvb  = (bf16_t*)(ws + 2 * szKV + 2 * szW);

    conv_w_kernel<<<768, 256, 0, stream>>>(Wq, Wk, Wv, Wqb, Wkb, Wvb);
    kv_proj_kernel<<<512, 256, 0, stream>>>(x, Wkb, bk, Wvb, bv, kbuf, vbuf);
    attn_kernel<<<256, 512, 0, stream>>>(Wqb, bq, kbuf, vbuf, x, gate, out);
}

// Round 13
// 124.739 us; speedup vs baseline: 1.3361x; 1.0061x over previous
//
#include <hip/hip_runtime.h>
#include <hip/hip_bf16.h>

typedef __bf16 bf16_t;
typedef __bf16 bf16x8 __attribute__((ext_vector_type(8)));
typedef float  f32x2  __attribute__((ext_vector_type(2)));
typedef float  f32x4  __attribute__((ext_vector_type(4)));
typedef float  f32x16 __attribute__((ext_vector_type(16)));

#define B_ 8
#define C_ 256
#define L_ 4096
#define M_ 2048
#define INV_SQRT2f 0.70710678118654752440f

typedef __attribute__((address_space(3))) void as3_void;
typedef __attribute__((address_space(1))) const void as1_cvoid;

__device__ __forceinline__ void gload_lds16(const void* g, void* l) {
    __builtin_amdgcn_global_load_lds((as1_cvoid*)g, (as3_void*)l, 16, 0, 0);
}

__device__ __forceinline__ const bf16x8* ldg8(const bf16_t* p) {
    return reinterpret_cast<const bf16x8*>(p);
}

__device__ __forceinline__ unsigned packbf(float a, float b) {
    unsigned short ua = __builtin_bit_cast(unsigned short, (bf16_t)a);
    unsigned short ub = __builtin_bit_cast(unsigned short, (bf16_t)b);
    return (unsigned)ua | ((unsigned)ub << 16);
}

// v_permlane32_swap_b32 — ONLY on operands with DISTINCT values (identical
// values coalesce into one register -> self-swap; round-8 bug).
__device__ __forceinline__ void pl32swapu(unsigned &a, unsigned &b) {
    asm("v_permlane32_swap_b32 %0, %1" : "+v"(a), "+v"(b));
}

// ---------------- kernel 0: weight conversion f32 -> bf16 (once) ----------------
__global__ __launch_bounds__(256) void conv_w_kernel(
    const float* __restrict__ Wq, const float* __restrict__ Wk, const float* __restrict__ Wv,
    bf16_t* __restrict__ Wqb, bf16_t* __restrict__ Wkb, bf16_t* __restrict__ Wvb) {
    int idx = blockIdx.x * 256 + threadIdx.x;      // 0..196607
    int which = idx >> 16;
    int off = idx & 65535;
    const float* src = (which == 0) ? Wq : ((which == 1) ? Wk : Wv);
    bf16_t* dst = (which == 0) ? Wqb : ((which == 1) ? Wkb : Wvb);
    dst[off] = (bf16_t)src[off];
}

// ================= kernel A: fused Haar + K-proj + V-proj =================
// 512 blocks (b, 32-m-tile) x 256 thr -> 2 blocks/CU, 2 waves/SIMD.
// Phase 1 uses a register-staged chunk pipeline: chunk cc+1's global loads
// fly while chunk cc's Haar/pack runs (T14).
__global__ __launch_bounds__(256, 2) void kv_proj_kernel(
    const float* __restrict__ x, const bf16_t* __restrict__ Wk, const float* __restrict__ bk,
    const bf16_t* __restrict__ Wv, const float* __restrict__ bv,
    bf16_t* __restrict__ kb, bf16_t* __restrict__ vb) {
    __shared__ __align__(16) char smem[16384 + 33280];
    char* xh = smem;                           // [32][512B] swizzled bf16
    float* tile = (float*)(smem + 16384);      // f32 [64][130] (f32x2-aligned)

    const int t = threadIdx.x;
    const int wave = t >> 6, lane = t & 63;
    const int l31 = lane & 31, hi = lane >> 5;
    const int bid = blockIdx.x;
    const int b = bid & 7;
    const int mt = bid >> 3;        // 0..63
    const int m0 = mt * 32;

    // ---- phase 1: build xh (4 c-chunks of 64), reg-staged pipeline ----
    const int c2 = (t & 31) * 2;    // c-pair base within chunk
    const int mg = t >> 5;          // 0..7
    const int lrow = t >> 5;        // load row base (0..7)
    const int lcp  = t & 31;        // load col pair
    f32x2 stage[8];
    {
        const float* xs = x + ((size_t)(b * C_) * L_) + 2 * m0;
#pragma unroll
        for (int j = 0; j < 8; ++j)
            stage[j] = *reinterpret_cast<const f32x2*>(xs + (size_t)(lrow + 8 * j) * L_ + lcp * 2);
    }
    for (int cc = 0; cc < 4; ++cc) {
        if (cc) __syncthreads();   // previous chunk's tile readers done
#pragma unroll
        for (int j = 0; j < 8; ++j)
            *reinterpret_cast<f32x2*>(tile + (lrow + 8 * j) * 130 + lcp * 2) = stage[j];
        __syncthreads();
        if (cc < 3) {
            const float* xs = x + ((size_t)(b * C_ + (cc + 1) * 64) * L_) + 2 * m0;
#pragma unroll
            for (int j = 0; j < 8; ++j)
                stage[j] = *reinterpret_cast<const f32x2*>(xs + (size_t)(lrow + 8 * j) * L_ + lcp * 2);
        }
#pragma unroll
        for (int i = 0; i < 4; ++i) {
            int m = mg * 4 + i;     // 0..31
            f32x2 pa = *reinterpret_cast<const f32x2*>(tile + c2 * 130 + 2 * m);
            f32x2 pb = *reinterpret_cast<const f32x2*>(tile + (c2 + 1) * 130 + 2 * m);
            float va  = (pa[0] - pa[1]) * INV_SQRT2f;
            float vb2 = (pb[0] - pb[1]) * INV_SQRT2f;
            int byte = m * 512 + ((((cc * 64 + c2) * 2)) ^ ((m & 7) << 4));
            *reinterpret_cast<unsigned*>(xh + byte) = packbf(va, vb2);
        }
    }
    __syncthreads();

    // ---- phase 2: merged K-proj + V-proj (shared xh reads, bf16 weights) ----
    const int oq = wave;           // o 64-block per wave
    f32x16 kacc[2], vacc[2];
#pragma unroll
    for (int ob = 0; ob < 2; ++ob) {
        float bko = bk[(oq * 2 + ob) * 32 + l31];
#pragma unroll
        for (int r = 0; r < 16; ++r) { kacc[ob][r] = bko; vacc[ob][r] = 0.f; }
    }
    const int s0 = (l31 & 7) << 4;
#pragma unroll
    for (int ks = 0; ks < 16; ++ks) {
        int cb = (ks * 16 + hi * 8) * 2;
        bf16x8 xv = *reinterpret_cast<const bf16x8*>(xh + l31 * 512 + (cb ^ s0));
#pragma unroll
        for (int ob = 0; ob < 2; ++ob) {
            int o = (oq * 2 + ob) * 32 + l31;
            bf16x8 bw = *ldg8(Wk + (size_t)o * C_ + ks * 16 + hi * 8);
            kacc[ob] = __builtin_amdgcn_mfma_f32_32x32x16_bf16(xv, bw, kacc[ob], 0, 0, 0);
            bf16x8 aw = *ldg8(Wv + (size_t)o * C_ + ks * 16 + hi * 8);
            vacc[ob] = __builtin_amdgcn_mfma_f32_32x32x16_bf16(aw, xv, vacc[ob], 0, 0, 0);
        }
    }
    bf16_t* kout = kb + (size_t)b * M_ * C_;
    bf16_t* vout = vb + (size_t)b * C_ * M_;
#pragma unroll
    for (int ob = 0; ob < 2; ++ob) {
        int o = (oq * 2 + ob) * 32 + l31;
#pragma unroll
        for (int r = 0; r < 16; ++r) {
            int mloc = (r & 3) + 8 * (r >> 2) + 4 * hi;
            kout[(size_t)(m0 + mloc) * C_ + o] = (bf16_t)kacc[ob][r];
        }
#pragma unroll
        for (int r = 0; r < 16; ++r) {
            int ov = (oq * 2 + ob) * 32 + (r & 3) + 8 * (r >> 2) + 4 * hi;
            vout[(size_t)ov * M_ + m0 + l31] = (bf16_t)(vacc[ob][r] + bv[ov]);
        }
    }
}

// ================= kernel B: attention with fused Q-projection =================
#define KT 64
#define NT (M_ / KT)   // 32

__global__ __launch_bounds__(512, 1) void attn_kernel(
    const bf16_t* __restrict__ Wq, const float* __restrict__ bq,
    const bf16_t* __restrict__ kb, const bf16_t* __restrict__ vb,
    const float* __restrict__ x, const float* __restrict__ gate, float* __restrict__ out) {
    __shared__ __align__(16) char smem[135168];
    char* Kbase_l = smem;
    char* Vbase_l = smem + 65536;

    const int t = threadIdx.x;
    const int wave = t >> 6, lane = t & 63;
    const int qg = wave & 3, mh = wave >> 2;
    const int l31 = lane & 31, hi = lane >> 5;
    const int bid = blockIdx.x;
    const int b = bid & 7;          // batch -> XCD affinity
    const int lt = bid >> 3;        // 0..31
    const int l0w = lt * 128 + qg * 32;

    bf16x8 qf[16];

    // ======== Q-projection prologue (scale 1/sqrt(C)=2^-4 folded into q) ========
    {
        float* tile = (float*)Vbase_l;   // f32 [64][130]
        char* xt = Kbase_l;              // [128][512B] bf16 swizzled
        const int cp2 = (t & 31) * 2;
        const int lg = t >> 5;           // 0..15
        const int lrow = t >> 6;         // load row base (0..7)
        const int lcp  = t & 63;         // load col pair
        f32x2 stage[8];
        {
            const float* xs = x + ((size_t)(b * C_) * L_) + lt * 128;
#pragma unroll
            for (int j = 0; j < 8; ++j)
                stage[j] = *reinterpret_cast<const f32x2*>(xs + (size_t)(lrow + 8 * j) * L_ + lcp * 2);
        }
        for (int cc = 0; cc < 4; ++cc) {
            if (cc) __syncthreads();
#pragma unroll
            for (int j = 0; j < 8; ++j)
                *reinterpret_cast<f32x2*>(tile + (lrow + 8 * j) * 130 + lcp * 2) = stage[j];
            __syncthreads();
            if (cc < 3) {
                const float* xs = x + ((size_t)(b * C_ + (cc + 1) * 64) * L_) + lt * 128;
#pragma unroll
                for (int j = 0; j < 8; ++j)
                    stage[j] = *reinterpret_cast<const f32x2*>(xs + (size_t)(lrow + 8 * j) * L_ + lcp * 2);
            }
#pragma unroll
            for (int i = 0; i < 8; ++i) {
                int l = lg * 8 + i;
                float va  = tile[cp2 * 130 + l];
                float vb2 = tile[(cp2 + 1) * 130 + l];
                int byte = l * 512 + ((((cc * 64 + cp2) * 2)) ^ ((l & 7) << 4));
                *reinterpret_cast<unsigned*>(xt + byte) = packbf(va, vb2);
            }
        }
        __syncthreads();

        const int ow = wave * 32;
        f32x16 qacc[4];
#pragma unroll
        for (int lb = 0; lb < 4; ++lb)
#pragma unroll
            for (int r = 0; r < 16; ++r) qacc[lb][r] = 0.f;
#pragma unroll
        for (int ks = 0; ks < 16; ++ks) {
            bf16x8 aw = *ldg8(Wq + (size_t)(ow + l31) * C_ + ks * 16 + hi * 8);
#pragma unroll
            for (int lb = 0; lb < 4; ++lb) {
                int lrow2 = lb * 32 + l31;
                bf16x8 bx = *reinterpret_cast<const bf16x8*>(
                    xt + lrow2 * 512 + (((ks * 16 + hi * 8) * 2) ^ ((lrow2 & 7) << 4)));
                qacc[lb] = __builtin_amdgcn_mfma_f32_32x32x16_bf16(aw, bx, qacc[lb], 0, 0, 0);
            }
        }
        __syncthreads();   // xt reads & tile use done; V-space becomes qt
        char* qt = Vbase_l;  // [128][512B] bf16 swizzled, holds q*2^-4
#pragma unroll
        for (int lb = 0; lb < 4; ++lb) {
            int l = lb * 32 + l31;
            int lsw = (l & 7) << 4;
#pragma unroll
            for (int q = 0; q < 4; ++q) {
                int o = ow + 4 * hi + 8 * q;
                f32x4 bq4 = *reinterpret_cast<const f32x4*>(bq + o);
                unsigned w0 = packbf((qacc[lb][q * 4 + 0] + bq4[0]) * 0.0625f,
                                     (qacc[lb][q * 4 + 1] + bq4[1]) * 0.0625f);
                unsigned w1 = packbf((qacc[lb][q * 4 + 2] + bq4[2]) * 0.0625f,
                                     (qacc[lb][q * 4 + 3] + bq4[3]) * 0.0625f);
                unsigned long long w = (unsigned long long)w0 | ((unsigned long long)w1 << 32);
                *reinterpret_cast<unsigned long long*>(qt + l * 512 + ((o * 2) ^ lsw)) = w;
            }
        }
        __syncthreads();
        const int qrow = qg * 32 + l31;
        const int qswz = (qrow & 7) << 4;
#pragma unroll
        for (int ks = 0; ks < 16; ++ks)
            qf[ks] = *reinterpret_cast<const bf16x8*>(
                qt + qrow * 512 + (((ks * 16 + hi * 8) * 2) ^ qswz));
        __syncthreads();   // qf read everywhere; K/V DMA may now overwrite
    }

    // ======== main flash loop (round-9 verified form) ========
    const char* Kg = (const char*)(kb + (size_t)b * M_ * C_);
    const char* Vg = (const char*)(vb + (size_t)b * C_ * M_);
    int ksrc[4], vsrc[4];
#pragma unroll
    for (int i = 0; i < 4; ++i) {
        int chunk = i * 8 + wave;
        int mr = chunk * 2 + (lane >> 5);
        ksrc[i] = mr * 512 + (((lane & 31) * 16) ^ ((mr & 7) << 4));
        int c = chunk * 8 + (lane >> 3);
        vsrc[i] = c * (M_ * 2) + (((lane & 7) * 16) ^ ((c & 7) << 4));
    }

#pragma unroll
    for (int i = 0; i < 4; ++i)
        gload_lds16(Kg + ksrc[i], Kbase_l + (i * 8 + wave) * 1024);
#pragma unroll
    for (int i = 0; i < 4; ++i)
        gload_lds16(Vg + vsrc[i], Vbase_l + (i * 8 + wave) * 1024);

    f32x16 acc[8];
#pragma unroll
    for (int cb = 0; cb < 8; ++cb)
#pragma unroll
        for (int r = 0; r < 16; ++r) acc[cb][r] = 0.f;
    float m_run = -INFINITY, l_run = 0.f;

    asm volatile("s_waitcnt vmcnt(0)" ::: "memory");
    __builtin_amdgcn_s_barrier();
    asm volatile("" ::: "memory");

    for (int kt = 0; kt < NT; ++kt) {
        const int cur = kt & 1;
        if (kt + 1 < NT) {
            const char* Kn = Kg + (size_t)(kt + 1) * 32768;
            char* Kd = Kbase_l + (cur ^ 1) * 32768;
#pragma unroll
            for (int i = 0; i < 4; ++i)
                gload_lds16(Kn + ksrc[i], Kd + (i * 8 + wave) * 1024);
            const char* Vn = Vg + (size_t)(kt + 1) * 128;
            char* Vd = Vbase_l + (cur ^ 1) * 32768;
#pragma unroll
            for (int i = 0; i < 4; ++i)
                gload_lds16(Vn + vsrc[i], Vd + (i * 8 + wave) * 1024);
        }

        // ---- S = K' x Q : single accumulator chain (register budget!) ----
        const char* Kc = Kbase_l + cur * 32768;
        const int mrow = mh * 32 + l31;
        const int msw = (mrow & 7) << 4;
        const int moff = mrow * 512;
        f32x16 s;
#pragma unroll
        for (int r = 0; r < 16; ++r) s[r] = 0.f;
        __builtin_amdgcn_s_setprio(1);
#pragma unroll
        for (int ks = 0; ks < 16; ++ks) {
            int cb2 = ks * 32 + hi * 16;
            bf16x8 a = *reinterpret_cast<const bf16x8*>(Kc + moff + (cb2 ^ msw));
            s = __builtin_amdgcn_mfma_f32_32x32x16_bf16(a, qf[ks], s, 0, 0, 0);
        }
        __builtin_amdgcn_s_setprio(0);

        // ---- online softmax over this m-half (scale already in q) ----
        float pv[16];
        float tm = -INFINITY;
#pragma unroll
        for (int r = 0; r < 16; ++r) {
            pv[r] = s[r];
            tm = fmaxf(tm, s[r]);
        }
        tm = fmaxf(tm, __shfl_xor(tm, 32));
        if (!__all(tm - m_run <= 8.0f)) {
            float m_new = fmaxf(m_run, tm);
            float corr = __expf(m_run - m_new);
#pragma unroll
            for (int cb = 0; cb < 8; ++cb)
#pragma unroll
                for (int r = 0; r < 16; ++r) acc[cb][r] *= corr;
            l_run *= corr;
            m_run = m_new;
        }
        float rs = 0.f;
#pragma unroll
        for (int i = 0; i < 16; ++i) { pv[i] = __expf(pv[i] - m_run); rs += pv[i]; }
        l_run += rs + __shfl_xor(rs, 32);

        // ---- build P B-frags: 4 permlane swaps (distinct operands) ----
        union PW { unsigned u[4]; bf16x8 v; };
        bf16x8 pfrag[2];
        {
            unsigned Ce0 = packbf(pv[0], pv[1]);
            unsigned Ce1 = packbf(pv[2], pv[3]);
            unsigned Ce2 = packbf(pv[4], pv[5]);
            unsigned Ce3 = packbf(pv[6], pv[7]);
            unsigned Co0 = packbf(pv[8], pv[9]);
            unsigned Co1 = packbf(pv[10], pv[11]);
            unsigned Co2 = packbf(pv[12], pv[13]);
            unsigned Co3 = packbf(pv[14], pv[15]);
            pl32swapu(Ce0, Ce2);
            pl32swapu(Ce1, Ce3);
            pl32swapu(Co0, Co2);
            pl32swapu(Co1, Co3);
            PW we, wo;
            we.u[0] = Ce0; we.u[1] = Ce1; we.u[2] = Ce2; we.u[3] = Ce3;
            wo.u[0] = Co0; wo.u[1] = Co1; wo.u[2] = Co2; wo.u[3] = Co3;
            pfrag[0] = we.v;
            pfrag[1] = wo.v;
        }

        const char* Vc = Vbase_l + cur * 32768;
        __builtin_amdgcn_s_setprio(1);
#pragma unroll
        for (int ks2 = 0; ks2 < 2; ++ks2) {
            int cb2 = (mh * 2 + ks2) * 32 + hi * 16;
#pragma unroll
            for (int cb = 0; cb < 8; ++cb) {
                int c = cb * 32 + l31;
                bf16x8 a = *reinterpret_cast<const bf16x8*>(Vc + c * 128 + (cb2 ^ ((c & 7) << 4)));
                acc[cb] = __builtin_amdgcn_mfma_f32_32x32x16_bf16(a, pfrag[ks2], acc[cb], 0, 0, 0);
            }
        }
        __builtin_amdgcn_s_setprio(0);

        asm volatile("s_waitcnt vmcnt(0)" ::: "memory");
        __builtin_amdgcn_s_barrier();
        asm volatile("" ::: "memory");
    }

    // ---- split-K merge between wave pairs (qg, 0) <-> (qg, 1) ----
    f32x2* mlb = (f32x2*)(smem + 131072);
    f32x2 myml; myml[0] = m_run; myml[1] = l_run;
    mlb[wave * 64 + lane] = myml;
    __syncthreads();
    f32x2 pml = mlb[(wave ^ 4) * 64 + lane];
    float m_star = fmaxf(m_run, pml[0]);
    float f_self = __expf(m_run - m_star);
    float f_peer = __expf(pml[0] - m_star);
    float l_tot = l_run * f_self + pml[1] * f_peer;
#pragma unroll
    for (int cb = 0; cb < 8; ++cb)
#pragma unroll
        for (int r = 0; r < 16; ++r) acc[cb][r] *= f_self;

    char* xbuf = smem;
    const int myoff = (qg * 2 + mh) * 16384;
    __syncthreads();
#pragma unroll
    for (int cbl = 0; cbl < 4; ++cbl)
#pragma unroll
        for (int q = 0; q < 4; ++q) {
            f32x4 chunk;
#pragma unroll
            for (int j = 0; j < 4; ++j) {
                float a_lo = acc[cbl][q * 4 + j];
                float a_hi = acc[4 + cbl][q * 4 + j];
                chunk[j] = mh ? a_lo : a_hi;
            }
            *reinterpret_cast<f32x4*>(xbuf + myoff + (cbl * 4 + q) * 1024 + lane * 16) = chunk;
        }
    __syncthreads();

    const int poff = (qg * 2 + (1 - mh)) * 16384;
    float gt = tanhf(gate[0]);
    float scale = gt / l_tot;
    const float* xp = x + (size_t)b * C_ * L_;
    float* op = out + (size_t)b * C_ * L_;
    int lcol = l0w + l31;
    const int cbase = mh * 4;
#pragma unroll
    for (int cbl = 0; cbl < 4; ++cbl) {
#pragma unroll
        for (int q = 0; q < 4; ++q) {
            f32x4 pc = *reinterpret_cast<const f32x4*>(xbuf + poff + (cbl * 4 + q) * 1024 + lane * 16);
#pragma unroll
            for (int j = 0; j < 4; ++j) {
                float a_lo = acc[cbl][q * 4 + j];
                float a_hi = acc[4 + cbl][q * 4 + j];
                float mine = mh ? a_hi : a_lo;
                int c = (cbase + cbl) * 32 + j + 8 * q + 4 * hi;
                size_t idx = (size_t)c * L_ + lcol;
                op[idx] = (mine + pc[j]) * scale + xp[idx];
            }
        }
    }
}

extern "C" void kernel_launch(void* const* d_in, const int* in_sizes, int n_in,
                              void* d_out, int out_size, void* d_ws, size_t ws_size,
                              hipStream_t stream) {
    const float* x    = (const float*)d_in[0];
    const float* Wq   = (const float*)d_in[1];
    const float* bq   = (const float*)d_in[2];
    const float* Wk   = (const float*)d_in[3];
    const float* bk   = (const float*)d_in[4];
    const float* Wv   = (const float*)d_in[5];
    const float* bv   = (const float*)d_in[6];
    const float* gate = (const float*)d_in[7];
    float* out = (float*)d_out;

    char* ws = (char*)d_ws;
    const size_t szKV = (size_t)B_ * M_ * C_ * 2;   // 8388608
    const size_t szW  = (size_t)C_ * C_ * 2;        // 131072
    bf16_t* kbuf = (bf16_t*)(ws);
    bf16_t* vbuf = (bf16_t*)(ws + szKV);
    bf16_t* Wqb  = (bf16_t*)(ws + 2 * szKV);
    bf16_t* Wkb  = (bf16_t*)(ws + 2 * szKV + szW);
    bf16_t* Wvb  = (bf16_t*)(ws + 2 * szKV + 2 * szW);

    conv_w_kernel<<<768, 256, 0, stream>>>(Wq, Wk, Wv, Wqb, Wkb, Wvb);
    kv_proj_kernel<<<512, 256, 0, stream>>>(x, Wkb, bk, Wvb, bv, kbuf, vbuf);
    attn_kernel<<<256, 512, 0, stream>>>(Wqb, bq, kbuf, vbuf, x, gate, out);
}

// Round 14
// 111.085 us; speedup vs baseline: 1.5003x; 1.1229x over previous
//
#include <hip/hip_runtime.h>
#include <hip/hip_bf16.h>

typedef __bf16 bf16_t;
typedef __bf16 bf16x8 __attribute__((ext_vector_type(8)));
typedef float  f32x2  __attribute__((ext_vector_type(2)));
typedef float  f32x4  __attribute__((ext_vector_type(4)));
typedef float  f32x16 __attribute__((ext_vector_type(16)));
typedef unsigned u32x2 __attribute__((ext_vector_type(2)));
typedef unsigned u32x4 __attribute__((ext_vector_type(4)));

#define B_ 8
#define C_ 256
#define L_ 4096
#define M_ 2048
#define INV_SQRT2f 0.70710678118654752440f

typedef __attribute__((address_space(3))) void as3_void;
typedef __attribute__((address_space(1))) const void as1_cvoid;

__device__ __forceinline__ void gload_lds16(const void* g, void* l) {
    __builtin_amdgcn_global_load_lds((as1_cvoid*)g, (as3_void*)l, 16, 0, 0);
}

__device__ __forceinline__ const bf16x8* ldg8(const bf16_t* p) {
    return reinterpret_cast<const bf16x8*>(p);
}

__device__ __forceinline__ unsigned packbf(float a, float b) {
    unsigned short ua = __builtin_bit_cast(unsigned short, (bf16_t)a);
    unsigned short ub = __builtin_bit_cast(unsigned short, (bf16_t)b);
    return (unsigned)ua | ((unsigned)ub << 16);
}

// v_permlane32_swap_b32 — ONLY on operands with DISTINCT values.
__device__ __forceinline__ void pl32swapu(unsigned &a, unsigned &b) {
    asm("v_permlane32_swap_b32 %0, %1" : "+v"(a), "+v"(b));
}

// swap bits 3 and 4 (the sigma c-permutation; involution)
__device__ __forceinline__ int bs34(int v) {
    return (v & ~0x18) | ((v & 8) << 1) | ((v & 16) >> 1);
}

// pack 4 f32 -> 4 fp8 e4m3 bytes (c-order 0..3)
__device__ __forceinline__ unsigned pk4fp8(float a, float b, float c, float d) {
    int u = __builtin_amdgcn_cvt_pk_fp8_f32(a, b, 0, false);
    u = __builtin_amdgcn_cvt_pk_fp8_f32(c, d, u, true);
    return (unsigned)u;
}

// ---------------- kernel 0: weight conversion f32 -> bf16 (once) ----------------
__global__ __launch_bounds__(256) void conv_w_kernel(
    const float* __restrict__ Wq, const float* __restrict__ Wk, const float* __restrict__ Wv,
    bf16_t* __restrict__ Wqb, bf16_t* __restrict__ Wkb, bf16_t* __restrict__ Wvb) {
    int idx = blockIdx.x * 256 + threadIdx.x;
    int which = idx >> 16;
    int off = idx & 65535;
    const float* src = (which == 0) ? Wq : ((which == 1) ? Wk : Wv);
    bf16_t* dst = (which == 0) ? Wqb : ((which == 1) ? Wkb : Wvb);
    dst[off] = (bf16_t)src[off];
}

// ================= kernel A: fused Haar + K-proj(fp8 out) + V-proj =================
__global__ __launch_bounds__(256, 2) void kv_proj_kernel(
    const float* __restrict__ x, const bf16_t* __restrict__ Wk, const float* __restrict__ bk,
    const bf16_t* __restrict__ Wv, const float* __restrict__ bv,
    unsigned char* __restrict__ kb8, bf16_t* __restrict__ vb) {
    __shared__ __align__(16) char smem[16384 + 33280];
    char* xh = smem;                           // [32][512B] swizzled bf16
    float* tile = (float*)(smem + 16384);      // f32 [64][130]

    const int t = threadIdx.x;
    const int wave = t >> 6, lane = t & 63;
    const int l31 = lane & 31, hi = lane >> 5;
    const int bid = blockIdx.x;
    const int b = bid & 7;
    const int mt = bid >> 3;        // 0..63
    const int m0 = mt * 32;

    // ---- phase 1: build xh (4 c-chunks of 64), reg-staged pipeline ----
    const int c2 = (t & 31) * 2;
    const int mg = t >> 5;
    const int lrow = t >> 5;
    const int lcp  = t & 31;
    f32x2 stage[8];
    {
        const float* xs = x + ((size_t)(b * C_) * L_) + 2 * m0;
#pragma unroll
        for (int j = 0; j < 8; ++j)
            stage[j] = *reinterpret_cast<const f32x2*>(xs + (size_t)(lrow + 8 * j) * L_ + lcp * 2);
    }
    for (int cc = 0; cc < 4; ++cc) {
        if (cc) __syncthreads();
#pragma unroll
        for (int j = 0; j < 8; ++j)
            *reinterpret_cast<f32x2*>(tile + (lrow + 8 * j) * 130 + lcp * 2) = stage[j];
        __syncthreads();
        if (cc < 3) {
            const float* xs = x + ((size_t)(b * C_ + (cc + 1) * 64) * L_) + 2 * m0;
#pragma unroll
            for (int j = 0; j < 8; ++j)
                stage[j] = *reinterpret_cast<const f32x2*>(xs + (size_t)(lrow + 8 * j) * L_ + lcp * 2);
        }
#pragma unroll
        for (int i = 0; i < 4; ++i) {
            int m = mg * 4 + i;
            f32x2 pa = *reinterpret_cast<const f32x2*>(tile + c2 * 130 + 2 * m);
            f32x2 pb = *reinterpret_cast<const f32x2*>(tile + (c2 + 1) * 130 + 2 * m);
            float va  = (pa[0] - pa[1]) * INV_SQRT2f;
            float vb2 = (pb[0] - pb[1]) * INV_SQRT2f;
            int byte = m * 512 + ((((cc * 64 + c2) * 2)) ^ ((m & 7) << 4));
            *reinterpret_cast<unsigned*>(xh + byte) = packbf(va, vb2);
        }
    }
    __syncthreads();

    // ---- phase 2: merged K-proj + V-proj (shared xh reads, bf16 weights) ----
    const int oq = wave;
    f32x16 kacc[2], vacc[2];
#pragma unroll
    for (int ob = 0; ob < 2; ++ob) {
        float bko = bk[(oq * 2 + ob) * 32 + l31];
#pragma unroll
        for (int r = 0; r < 16; ++r) { kacc[ob][r] = bko; vacc[ob][r] = 0.f; }
    }
    const int s0 = (l31 & 7) << 4;
#pragma unroll
    for (int ks = 0; ks < 16; ++ks) {
        int cb = (ks * 16 + hi * 8) * 2;
        bf16x8 xv = *reinterpret_cast<const bf16x8*>(xh + l31 * 512 + (cb ^ s0));
#pragma unroll
        for (int ob = 0; ob < 2; ++ob) {
            int o = (oq * 2 + ob) * 32 + l31;
            bf16x8 bw = *ldg8(Wk + (size_t)o * C_ + ks * 16 + hi * 8);
            kacc[ob] = __builtin_amdgcn_mfma_f32_32x32x16_bf16(xv, bw, kacc[ob], 0, 0, 0);
            bf16x8 aw = *ldg8(Wv + (size_t)o * C_ + ks * 16 + hi * 8);
            vacc[ob] = __builtin_amdgcn_mfma_f32_32x32x16_bf16(aw, xv, vacc[ob], 0, 0, 0);
        }
    }
    // K out: fp8, sigma(bit3<->4)-permuted channel index
    unsigned char* kout8 = kb8 + (size_t)b * M_ * C_;
    bf16_t* vout = vb + (size_t)b * C_ * M_;
#pragma unroll
    for (int ob = 0; ob < 2; ++ob) {
        int o = (oq * 2 + ob) * 32 + l31;
        int g = bs34(o);
#pragma unroll
        for (int r = 0; r < 16; ++r) {
            int mloc = (r & 3) + 8 * (r >> 2) + 4 * hi;
            unsigned p = (unsigned)__builtin_amdgcn_cvt_pk_fp8_f32(kacc[ob][r], kacc[ob][r], 0, false);
            kout8[(size_t)(m0 + mloc) * C_ + g] = (unsigned char)(p & 0xFF);
        }
#pragma unroll
        for (int r = 0; r < 16; ++r) {
            int ov = (oq * 2 + ob) * 32 + (r & 3) + 8 * (r >> 2) + 4 * hi;
            vout[(size_t)ov * M_ + m0 + l31] = (bf16_t)(vacc[ob][r] + bv[ov]);
        }
    }
}

// ================= kernel B: attention, fp8 S-phase =================
#define KT 64
#define NT (M_ / KT)   // 32

// LDS map: [0,32K) K fp8 dbuf | [32K,96K) V bf16 dbuf | [96K,131.5K) tile scratch
// prologue: xt(64K)=V space, tile=scratch, qt(32K fp8)=K space; mlb @131072.
__global__ __launch_bounds__(512, 1) void attn_kernel(
    const bf16_t* __restrict__ Wq, const float* __restrict__ bq,
    const unsigned char* __restrict__ kb8, const bf16_t* __restrict__ vb,
    const float* __restrict__ x, const float* __restrict__ gate, float* __restrict__ out) {
    __shared__ __align__(16) char smem[135168];
    char* Kbase_l = smem;                 // 32KB (K fp8 dbuf / qt)
    char* Vbase_l = smem + 32768;         // 64KB (V dbuf / xt)
    float* tile   = (float*)(smem + 98304); // 33280B scratch

    const int t = threadIdx.x;
    const int wave = t >> 6, lane = t & 63;
    const int qg = wave & 3, mh = wave >> 2;
    const int l31 = lane & 31, hi = lane >> 5;
    const int bid = blockIdx.x;
    const int b = bid & 7;
    const int lt = bid >> 3;
    const int l0w = lt * 128 + qg * 32;

    long qf2[16];   // fp8 B-frags: qf2[ks] = Q_fp8[query l31][c-slice], 2 regs each

    // ======== Q-projection prologue (bf16 GEMM, fp8 pack; scale 2^-4 folded) ========
    {
        char* xt = Vbase_l;              // [128][512B] bf16 swizzled
        const int cp2 = (t & 31) * 2;
        const int lg = t >> 5;
        const int lrow = t >> 6;
        const int lcp  = t & 63;
        f32x2 stage[8];
        {
            const float* xs = x + ((size_t)(b * C_) * L_) + lt * 128;
#pragma unroll
            for (int j = 0; j < 8; ++j)
                stage[j] = *reinterpret_cast<const f32x2*>(xs + (size_t)(lrow + 8 * j) * L_ + lcp * 2);
        }
        for (int cc = 0; cc < 4; ++cc) {
            if (cc) __syncthreads();
#pragma unroll
            for (int j = 0; j < 8; ++j)
                *reinterpret_cast<f32x2*>(tile + (lrow + 8 * j) * 130 + lcp * 2) = stage[j];
            __syncthreads();
            if (cc < 3) {
                const float* xs = x + ((size_t)(b * C_ + (cc + 1) * 64) * L_) + lt * 128;
#pragma unroll
                for (int j = 0; j < 8; ++j)
                    stage[j] = *reinterpret_cast<const f32x2*>(xs + (size_t)(lrow + 8 * j) * L_ + lcp * 2);
            }
#pragma unroll
            for (int i = 0; i < 8; ++i) {
                int l = lg * 8 + i;
                float va  = tile[cp2 * 130 + l];
                float vb2 = tile[(cp2 + 1) * 130 + l];
                int byte = l * 512 + ((((cc * 64 + cp2) * 2)) ^ ((l & 7) << 4));
                *reinterpret_cast<unsigned*>(xt + byte) = packbf(va, vb2);
            }
        }
        __syncthreads();

        const int ow = wave * 32;
        f32x16 qacc[4];
#pragma unroll
        for (int lb = 0; lb < 4; ++lb)
#pragma unroll
            for (int r = 0; r < 16; ++r) qacc[lb][r] = 0.f;
#pragma unroll
        for (int ks = 0; ks < 16; ++ks) {
            bf16x8 aw = *ldg8(Wq + (size_t)(ow + l31) * C_ + ks * 16 + hi * 8);
#pragma unroll
            for (int lb = 0; lb < 4; ++lb) {
                int lrow2 = lb * 32 + l31;
                bf16x8 bx = *reinterpret_cast<const bf16x8*>(
                    xt + lrow2 * 512 + (((ks * 16 + hi * 8) * 2) ^ ((lrow2 & 7) << 4)));
                qacc[lb] = __builtin_amdgcn_mfma_f32_32x32x16_bf16(aw, bx, qacc[lb], 0, 0, 0);
            }
        }
        // write qt: fp8 [128 queries][256B], sigma-permuted c, swz=((l&7)<<4)
        char* qt = Kbase_l;
#pragma unroll
        for (int lb = 0; lb < 4; ++lb) {
            int l = lb * 32 + l31;
            int lsw = (l & 7) << 4;
#pragma unroll
            for (int q = 0; q < 4; ++q) {
                int o0 = ow + 4 * hi + 8 * q;
                f32x4 bq4 = *reinterpret_cast<const f32x4*>(bq + o0);
                unsigned w = pk4fp8((qacc[lb][q * 4 + 0] + bq4[0]) * 0.0625f,
                                    (qacc[lb][q * 4 + 1] + bq4[1]) * 0.0625f,
                                    (qacc[lb][q * 4 + 2] + bq4[2]) * 0.0625f,
                                    (qacc[lb][q * 4 + 3] + bq4[3]) * 0.0625f);
                int pos0 = bs34(o0);
                *reinterpret_cast<unsigned*>(qt + l * 256 + (pos0 ^ lsw)) = w;
            }
        }
        __syncthreads();
        // read qf2: 8 x b128, each = 2 MFMA steps
        const int qrow = qg * 32 + l31;
        const int qswz = (qrow & 7) << 4;
#pragma unroll
        for (int ks2 = 0; ks2 < 8; ++ks2) {
            u32x4 v = *reinterpret_cast<const u32x4*>(
                qt + qrow * 256 + ((ks2 * 32 + hi * 16) ^ qswz));
            u32x2 lo; lo[0] = v[0]; lo[1] = v[1];
            u32x2 hi2; hi2[0] = v[2]; hi2[1] = v[3];
            qf2[2 * ks2]     = __builtin_bit_cast(long, lo);
            qf2[2 * ks2 + 1] = __builtin_bit_cast(long, hi2);
        }
        __syncthreads();   // qf2 everywhere; K/V DMA may overwrite
    }

    // ======== main flash loop ========
    const char* Kg = (const char*)(kb8 + (size_t)b * M_ * C_);       // fp8 [M][256B]
    const char* Vg = (const char*)(vb + (size_t)b * C_ * M_);
    int ksrc[2], vsrc[4];
#pragma unroll
    for (int i = 0; i < 2; ++i) {
        int chunk = i * 8 + wave;                 // 0..15 (1KB chunks, 16KB tile)
        int mr = chunk * 4 + (lane >> 4);         // K row 0..63
        ksrc[i] = mr * 256 + (((lane & 15) * 16) ^ ((mr & 7) << 4));
    }
#pragma unroll
    for (int i = 0; i < 4; ++i) {
        int chunk = i * 8 + wave;
        int c = chunk * 8 + (lane >> 3);
        vsrc[i] = c * (M_ * 2) + (((lane & 7) * 16) ^ ((c & 7) << 4));
    }

#pragma unroll
    for (int i = 0; i < 2; ++i)
        gload_lds16(Kg + ksrc[i], Kbase_l + (i * 8 + wave) * 1024);
#pragma unroll
    for (int i = 0; i < 4; ++i)
        gload_lds16(Vg + vsrc[i], Vbase_l + (i * 8 + wave) * 1024);

    f32x16 acc[8];
#pragma unroll
    for (int cb = 0; cb < 8; ++cb)
#pragma unroll
        for (int r = 0; r < 16; ++r) acc[cb][r] = 0.f;
    float m_run = -INFINITY, l_run = 0.f;

    asm volatile("s_waitcnt vmcnt(0)" ::: "memory");
    __builtin_amdgcn_s_barrier();
    asm volatile("" ::: "memory");

    for (int kt = 0; kt < NT; ++kt) {
        const int cur = kt & 1;
        if (kt + 1 < NT) {
            const char* Kn = Kg + (size_t)(kt + 1) * 16384;
            char* Kd = Kbase_l + (cur ^ 1) * 16384;
#pragma unroll
            for (int i = 0; i < 2; ++i)
                gload_lds16(Kn + ksrc[i], Kd + (i * 8 + wave) * 1024);
            const char* Vn = Vg + (size_t)(kt + 1) * 128;
            char* Vd = Vbase_l + (cur ^ 1) * 32768;
#pragma unroll
            for (int i = 0; i < 4; ++i)
                gload_lds16(Vn + vsrc[i], Vd + (i * 8 + wave) * 1024);
        }

        // ---- S = K' x Q (fp8): 8 reads x 2 MFMA ----
        const char* Kc = Kbase_l + cur * 16384;
        const int mrow = mh * 32 + l31;
        const int msw = (mrow & 7) << 4;
        const int moff = mrow * 256;
        f32x16 s;
#pragma unroll
        for (int r = 0; r < 16; ++r) s[r] = 0.f;
        __builtin_amdgcn_s_setprio(1);
#pragma unroll
        for (int ks2 = 0; ks2 < 8; ++ks2) {
            u32x4 kv = *reinterpret_cast<const u32x4*>(
                Kc + moff + ((ks2 * 32 + hi * 16) ^ msw));
            u32x2 lo; lo[0] = kv[0]; lo[1] = kv[1];
            u32x2 hi2; hi2[0] = kv[2]; hi2[1] = kv[3];
            long a_e = __builtin_bit_cast(long, lo);
            long a_o = __builtin_bit_cast(long, hi2);
            s = __builtin_amdgcn_mfma_f32_32x32x16_fp8_fp8(a_e, qf2[2 * ks2], s, 0, 0, 0);
            s = __builtin_amdgcn_mfma_f32_32x32x16_fp8_fp8(a_o, qf2[2 * ks2 + 1], s, 0, 0, 0);
        }
        __builtin_amdgcn_s_setprio(0);

        // ---- online softmax (scale already in q) ----
        float pv[16];
        float tm = -INFINITY;
#pragma unroll
        for (int r = 0; r < 16; ++r) {
            pv[r] = s[r];
            tm = fmaxf(tm, s[r]);
        }
        tm = fmaxf(tm, __shfl_xor(tm, 32));
        if (!__all(tm - m_run <= 8.0f)) {
            float m_new = fmaxf(m_run, tm);
            float corr = __expf(m_run - m_new);
#pragma unroll
            for (int cb = 0; cb < 8; ++cb)
#pragma unroll
                for (int r = 0; r < 16; ++r) acc[cb][r] *= corr;
            l_run *= corr;
            m_run = m_new;
        }
        float rs = 0.f;
#pragma unroll
        for (int i = 0; i < 16; ++i) { pv[i] = __expf(pv[i] - m_run); rs += pv[i]; }
        l_run += rs + __shfl_xor(rs, 32);

        // ---- build P B-frags (bf16): 4 permlane swaps ----
        union PW { unsigned u[4]; bf16x8 v; };
        bf16x8 pfrag[2];
        {
            unsigned Ce0 = packbf(pv[0], pv[1]);
            unsigned Ce1 = packbf(pv[2], pv[3]);
            unsigned Ce2 = packbf(pv[4], pv[5]);
            unsigned Ce3 = packbf(pv[6], pv[7]);
            unsigned Co0 = packbf(pv[8], pv[9]);
            unsigned Co1 = packbf(pv[10], pv[11]);
            unsigned Co2 = packbf(pv[12], pv[13]);
            unsigned Co3 = packbf(pv[14], pv[15]);
            pl32swapu(Ce0, Ce2);
            pl32swapu(Ce1, Ce3);
            pl32swapu(Co0, Co2);
            pl32swapu(Co1, Co3);
            PW we, wo;
            we.u[0] = Ce0; we.u[1] = Ce1; we.u[2] = Ce2; we.u[3] = Ce3;
            wo.u[0] = Co0; wo.u[1] = Co1; wo.u[2] = Co2; wo.u[3] = Co3;
            pfrag[0] = we.v;
            pfrag[1] = wo.v;
        }

        const char* Vc = Vbase_l + cur * 32768;
        __builtin_amdgcn_s_setprio(1);
#pragma unroll
        for (int ks2 = 0; ks2 < 2; ++ks2) {
            int cb2 = (mh * 2 + ks2) * 32 + hi * 16;
#pragma unroll
            for (int cb = 0; cb < 8; ++cb) {
                int c = cb * 32 + l31;
                bf16x8 a = *reinterpret_cast<const bf16x8*>(Vc + c * 128 + (cb2 ^ ((c & 7) << 4)));
                acc[cb] = __builtin_amdgcn_mfma_f32_32x32x16_bf16(a, pfrag[ks2], acc[cb], 0, 0, 0);
            }
        }
        __builtin_amdgcn_s_setprio(0);

        asm volatile("s_waitcnt vmcnt(0)" ::: "memory");
        __builtin_amdgcn_s_barrier();
        asm volatile("" ::: "memory");
    }

    // ---- split-K merge between wave pairs (qg, 0) <-> (qg, 1) ----
    f32x2* mlb = (f32x2*)(smem + 131072);
    f32x2 myml; myml[0] = m_run; myml[1] = l_run;
    mlb[wave * 64 + lane] = myml;
    __syncthreads();
    f32x2 pml = mlb[(wave ^ 4) * 64 + lane];
    float m_star = fmaxf(m_run, pml[0]);
    float f_self = __expf(m_run - m_star);
    float f_peer = __expf(pml[0] - m_star);
    float l_tot = l_run * f_self + pml[1] * f_peer;
#pragma unroll
    for (int cb = 0; cb < 8; ++cb)
#pragma unroll
        for (int r = 0; r < 16; ++r) acc[cb][r] *= f_self;

    char* xbuf = smem;
    const int myoff = (qg * 2 + mh) * 16384;
    __syncthreads();
#pragma unroll
    for (int cbl = 0; cbl < 4; ++cbl)
#pragma unroll
        for (int q = 0; q < 4; ++q) {
            f32x4 chunk;
#pragma unroll
            for (int j = 0; j < 4; ++j) {
                float a_lo = acc[cbl][q * 4 + j];
                float a_hi = acc[4 + cbl][q * 4 + j];
                chunk[j] = mh ? a_lo : a_hi;
            }
            *reinterpret_cast<f32x4*>(xbuf + myoff + (cbl * 4 + q) * 1024 + lane * 16) = chunk;
        }
    __syncthreads();

    const int poff = (qg * 2 + (1 - mh)) * 16384;
    float gt = tanhf(gate[0]);
    float scale = gt / l_tot;
    const float* xp = x + (size_t)b * C_ * L_;
    float* op = out + (size_t)b * C_ * L_;
    int lcol = l0w + l31;
    const int cbase = mh * 4;
#pragma unroll
    for (int cbl = 0; cbl < 4; ++cbl) {
#pragma unroll
        for (int q = 0; q < 4; ++q) {
            f32x4 pc = *reinterpret_cast<const f32x4*>(xbuf + poff + (cbl * 4 + q) * 1024 + lane * 16);
#pragma unroll
            for (int j = 0; j < 4; ++j) {
                float a_lo = acc[cbl][q * 4 + j];
                float a_hi = acc[4 + cbl][q * 4 + j];
                float mine = mh ? a_hi : a_lo;
                int c = (cbase + cbl) * 32 + j + 8 * q + 4 * hi;
                size_t idx = (size_t)c * L_ + lcol;
                op[idx] = (mine + pc[j]) * scale + xp[idx];
            }
        }
    }
}

extern "C" void kernel_launch(void* const* d_in, const int* in_sizes, int n_in,
                              void* d_out, int out_size, void* d_ws, size_t ws_size,
                              hipStream_t stream) {
    const float* x    = (const float*)d_in[0];
    const float* Wq   = (const float*)d_in[1];
    const float* bq   = (const float*)d_in[2];
    const float* Wk   = (const float*)d_in[3];
    const float* bk   = (const float*)d_in[4];
    const float* Wv   = (const float*)d_in[5];
    const float* bv   = (const float*)d_in[6];
    const float* gate = (const float*)d_in[7];
    float* out = (float*)d_out;

    char* ws = (char*)d_ws;
    const size_t szK8 = (size_t)B_ * M_ * C_;        // 4194304 (fp8)
    const size_t szV  = (size_t)B_ * M_ * C_ * 2;    // 8388608
    const size_t szW  = (size_t)C_ * C_ * 2;         // 131072
    unsigned char* kbuf8 = (unsigned char*)(ws);
    bf16_t* vbuf = (bf16_t*)(ws + szK8);
    bf16_t* Wqb  = (bf16_t*)(ws + szK8 + szV);
    bf16_t* Wkb  = (bf16_t*)(ws + szK8 + szV + szW);
    bf16_t* Wvb  = (bf16_t*)(ws + szK8 + szV + 2 * szW);

    conv_w_kernel<<<768, 256, 0, stream>>>(Wq, Wk, Wv, Wqb, Wkb, Wvb);
    kv_proj_kernel<<<512, 256, 0, stream>>>(x, Wkb, bk, Wvb, bv, kbuf8, vbuf);
    attn_kernel<<<256, 512, 0, stream>>>(Wqb, bq, kbuf8, vbuf, x, gate, out);
}

// Round 15
// 102.635 us; speedup vs baseline: 1.6239x; 1.0823x over previous
//
#include <hip/hip_runtime.h>
#include <hip/hip_bf16.h>

typedef __bf16 bf16_t;
typedef __bf16 bf16x8 __attribute__((ext_vector_type(8)));
typedef float  f32x2  __attribute__((ext_vector_type(2)));
typedef float  f32x4  __attribute__((ext_vector_type(4)));
typedef float  f32x16 __attribute__((ext_vector_type(16)));
typedef unsigned u32x2 __attribute__((ext_vector_type(2)));
typedef unsigned u32x4 __attribute__((ext_vector_type(4)));

#define B_ 8
#define C_ 256
#define L_ 4096
#define M_ 2048
#define INV_SQRT2f 0.70710678118654752440f

typedef __attribute__((address_space(3))) void as3_void;
typedef __attribute__((address_space(1))) const void as1_cvoid;

__device__ __forceinline__ void gload_lds16(const void* g, void* l) {
    __builtin_amdgcn_global_load_lds((as1_cvoid*)g, (as3_void*)l, 16, 0, 0);
}

__device__ __forceinline__ const bf16x8* ldg8(const bf16_t* p) {
    return reinterpret_cast<const bf16x8*>(p);
}

__device__ __forceinline__ unsigned packbf(float a, float b) {
    unsigned short ua = __builtin_bit_cast(unsigned short, (bf16_t)a);
    unsigned short ub = __builtin_bit_cast(unsigned short, (bf16_t)b);
    return (unsigned)ua | ((unsigned)ub << 16);
}

// v_permlane32_swap_b32 — ONLY on operands with DISTINCT values.
__device__ __forceinline__ void pl32swapu(unsigned &a, unsigned &b) {
    asm("v_permlane32_swap_b32 %0, %1" : "+v"(a), "+v"(b));
}

// swap bits 3 and 4 (sigma c-permutation for K/Q; involution)
__device__ __forceinline__ int bs34(int v) {
    return (v & ~0x18) | ((v & 8) << 1) | ((v & 16) >> 1);
}

// pack 4 f32 -> 4 fp8 e4m3 bytes (ascending byte order)
__device__ __forceinline__ unsigned pk4fp8(float a, float b, float c, float d) {
    int u = __builtin_amdgcn_cvt_pk_fp8_f32(a, b, 0, false);
    u = __builtin_amdgcn_cvt_pk_fp8_f32(c, d, u, true);
    return (unsigned)u;
}

// ---------------- kernel 0: weight conversion f32 -> bf16 (once) ----------------
__global__ __launch_bounds__(256) void conv_w_kernel(
    const float* __restrict__ Wq, const float* __restrict__ Wk, const float* __restrict__ Wv,
    bf16_t* __restrict__ Wqb, bf16_t* __restrict__ Wkb, bf16_t* __restrict__ Wvb) {
    int idx = blockIdx.x * 256 + threadIdx.x;
    int which = idx >> 16;
    int off = idx & 65535;
    const float* src = (which == 0) ? Wq : ((which == 1) ? Wk : Wv);
    bf16_t* dst = (which == 0) ? Wqb : ((which == 1) ? Wkb : Wvb);
    dst[off] = (bf16_t)src[off];
}

// ================= kernel A: fused Haar + K-proj(fp8) + V-proj(fp8) =================
__global__ __launch_bounds__(256, 2) void kv_proj_kernel(
    const float* __restrict__ x, const bf16_t* __restrict__ Wk, const float* __restrict__ bk,
    const bf16_t* __restrict__ Wv, const float* __restrict__ bv,
    unsigned char* __restrict__ kb8, unsigned char* __restrict__ vb8) {
    __shared__ __align__(16) char smem[16384 + 33280];
    char* xh = smem;                           // [32][512B] swizzled bf16
    float* tile = (float*)(smem + 16384);      // f32 [64][130]

    const int t = threadIdx.x;
    const int wave = t >> 6, lane = t & 63;
    const int l31 = lane & 31, hi = lane >> 5;
    const int bid = blockIdx.x;
    const int b = bid & 7;
    const int mt = bid >> 3;        // 0..63
    const int m0 = mt * 32;

    // ---- phase 1: build xh (4 c-chunks of 64), reg-staged pipeline ----
    const int c2 = (t & 31) * 2;
    const int mg = t >> 5;
    const int lrow = t >> 5;
    const int lcp  = t & 31;
    f32x2 stage[8];
    {
        const float* xs = x + ((size_t)(b * C_) * L_) + 2 * m0;
#pragma unroll
        for (int j = 0; j < 8; ++j)
            stage[j] = *reinterpret_cast<const f32x2*>(xs + (size_t)(lrow + 8 * j) * L_ + lcp * 2);
    }
    for (int cc = 0; cc < 4; ++cc) {
        if (cc) __syncthreads();
#pragma unroll
        for (int j = 0; j < 8; ++j)
            *reinterpret_cast<f32x2*>(tile + (lrow + 8 * j) * 130 + lcp * 2) = stage[j];
        __syncthreads();
        if (cc < 3) {
            const float* xs = x + ((size_t)(b * C_ + (cc + 1) * 64) * L_) + 2 * m0;
#pragma unroll
            for (int j = 0; j < 8; ++j)
                stage[j] = *reinterpret_cast<const f32x2*>(xs + (size_t)(lrow + 8 * j) * L_ + lcp * 2);
        }
#pragma unroll
        for (int i = 0; i < 4; ++i) {
            int m = mg * 4 + i;
            f32x2 pa = *reinterpret_cast<const f32x2*>(tile + c2 * 130 + 2 * m);
            f32x2 pb = *reinterpret_cast<const f32x2*>(tile + (c2 + 1) * 130 + 2 * m);
            float va  = (pa[0] - pa[1]) * INV_SQRT2f;
            float vb2 = (pb[0] - pb[1]) * INV_SQRT2f;
            int byte = m * 512 + ((((cc * 64 + c2) * 2)) ^ ((m & 7) << 4));
            *reinterpret_cast<unsigned*>(xh + byte) = packbf(va, vb2);
        }
    }
    __syncthreads();

    // ---- phase 2: merged K-proj + V-proj (shared xh reads, bf16 weights) ----
    const int oq = wave;
    f32x16 kacc[2], vacc[2];
#pragma unroll
    for (int ob = 0; ob < 2; ++ob) {
        float bko = bk[(oq * 2 + ob) * 32 + l31];
#pragma unroll
        for (int r = 0; r < 16; ++r) { kacc[ob][r] = bko; vacc[ob][r] = 0.f; }
    }
    const int s0 = (l31 & 7) << 4;
#pragma unroll
    for (int ks = 0; ks < 16; ++ks) {
        int cb = (ks * 16 + hi * 8) * 2;
        bf16x8 xv = *reinterpret_cast<const bf16x8*>(xh + l31 * 512 + (cb ^ s0));
#pragma unroll
        for (int ob = 0; ob < 2; ++ob) {
            int o = (oq * 2 + ob) * 32 + l31;
            bf16x8 bw = *ldg8(Wk + (size_t)o * C_ + ks * 16 + hi * 8);
            kacc[ob] = __builtin_amdgcn_mfma_f32_32x32x16_bf16(xv, bw, kacc[ob], 0, 0, 0);
            bf16x8 aw = *ldg8(Wv + (size_t)o * C_ + ks * 16 + hi * 8);
            vacc[ob] = __builtin_amdgcn_mfma_f32_32x32x16_bf16(aw, xv, vacc[ob], 0, 0, 0);
        }
    }
    // K out: fp8, sigma-permuted channels. V out: fp8 [C][M], plain.
    unsigned char* kout8 = kb8 + (size_t)b * M_ * C_;
    unsigned char* vout8 = vb8 + (size_t)b * C_ * M_;
#pragma unroll
    for (int ob = 0; ob < 2; ++ob) {
        int o = (oq * 2 + ob) * 32 + l31;
        int g = bs34(o);
#pragma unroll
        for (int r = 0; r < 16; ++r) {
            int mloc = (r & 3) + 8 * (r >> 2) + 4 * hi;
            unsigned p = (unsigned)__builtin_amdgcn_cvt_pk_fp8_f32(kacc[ob][r], kacc[ob][r], 0, false);
            kout8[(size_t)(m0 + mloc) * C_ + g] = (unsigned char)(p & 0xFF);
        }
#pragma unroll
        for (int r = 0; r < 16; ++r) {
            int ov = (oq * 2 + ob) * 32 + (r & 3) + 8 * (r >> 2) + 4 * hi;
            float val = vacc[ob][r] + bv[ov];
            unsigned p = (unsigned)__builtin_amdgcn_cvt_pk_fp8_f32(val, val, 0, false);
            vout8[(size_t)ov * M_ + m0 + l31] = (unsigned char)(p & 0xFF);
        }
    }
}

// ================= kernel B: attention, fp8 S and PV =================
#define KT 64
#define NT (M_ / KT)   // 32

// LDS map (main loop): K fp8 dbuf [0,32K) | V fp8 [c][72B] dbuf [32768, 69632)
// prologue: qt @0 (32K fp8), xt @32768 (64K), tile @98304; mlb @131072.
__global__ __launch_bounds__(512, 1) void attn_kernel(
    const bf16_t* __restrict__ Wq, const float* __restrict__ bq,
    const unsigned char* __restrict__ kb8, const unsigned char* __restrict__ vb8,
    const float* __restrict__ x, const float* __restrict__ gate, float* __restrict__ out) {
    __shared__ __align__(16) char smem[135168];
    char* Kbase_l = smem;                   // 32KB K fp8 dbuf / qt
    float* tile   = (float*)(smem + 98304); // prologue scratch

    const int t = threadIdx.x;
    const int wave = t >> 6, lane = t & 63;
    const int qg = wave & 3, mh = wave >> 2;
    const int l31 = lane & 31, hi = lane >> 5;
    const int bid = blockIdx.x;
    const int b = bid & 7;
    const int lt = bid >> 3;
    const int l0w = lt * 128 + qg * 32;

    long qf2[16];   // fp8 Q B-frags

    // ======== Q-projection prologue (bf16 GEMM, fp8 pack; scale 2^-4 folded) ========
    {
        char* xt = smem + 32768;         // [128][512B] bf16 swizzled
        const int cp2 = (t & 31) * 2;
        const int lg = t >> 5;
        const int lrow = t >> 6;
        const int lcp  = t & 63;
        f32x2 stage[8];
        {
            const float* xs = x + ((size_t)(b * C_) * L_) + lt * 128;
#pragma unroll
            for (int j = 0; j < 8; ++j)
                stage[j] = *reinterpret_cast<const f32x2*>(xs + (size_t)(lrow + 8 * j) * L_ + lcp * 2);
        }
        for (int cc = 0; cc < 4; ++cc) {
            if (cc) __syncthreads();
#pragma unroll
            for (int j = 0; j < 8; ++j)
                *reinterpret_cast<f32x2*>(tile + (lrow + 8 * j) * 130 + lcp * 2) = stage[j];
            __syncthreads();
            if (cc < 3) {
                const float* xs = x + ((size_t)(b * C_ + (cc + 1) * 64) * L_) + lt * 128;
#pragma unroll
                for (int j = 0; j < 8; ++j)
                    stage[j] = *reinterpret_cast<const f32x2*>(xs + (size_t)(lrow + 8 * j) * L_ + lcp * 2);
            }
#pragma unroll
            for (int i = 0; i < 8; ++i) {
                int l = lg * 8 + i;
                float va  = tile[cp2 * 130 + l];
                float vb2 = tile[(cp2 + 1) * 130 + l];
                int byte = l * 512 + ((((cc * 64 + cp2) * 2)) ^ ((l & 7) << 4));
                *reinterpret_cast<unsigned*>(xt + byte) = packbf(va, vb2);
            }
        }
        __syncthreads();

        const int ow = wave * 32;
        f32x16 qacc[4];
#pragma unroll
        for (int lb = 0; lb < 4; ++lb)
#pragma unroll
            for (int r = 0; r < 16; ++r) qacc[lb][r] = 0.f;
#pragma unroll
        for (int ks = 0; ks < 16; ++ks) {
            bf16x8 aw = *ldg8(Wq + (size_t)(ow + l31) * C_ + ks * 16 + hi * 8);
#pragma unroll
            for (int lb = 0; lb < 4; ++lb) {
                int lrow2 = lb * 32 + l31;
                bf16x8 bx = *reinterpret_cast<const bf16x8*>(
                    xt + lrow2 * 512 + (((ks * 16 + hi * 8) * 2) ^ ((lrow2 & 7) << 4)));
                qacc[lb] = __builtin_amdgcn_mfma_f32_32x32x16_bf16(aw, bx, qacc[lb], 0, 0, 0);
            }
        }
        // qt: fp8 [128][256B], sigma-permuted c, swz=((l&7)<<4)
        char* qt = Kbase_l;
#pragma unroll
        for (int lb = 0; lb < 4; ++lb) {
            int l = lb * 32 + l31;
            int lsw = (l & 7) << 4;
#pragma unroll
            for (int q = 0; q < 4; ++q) {
                int o0 = ow + 4 * hi + 8 * q;
                f32x4 bq4 = *reinterpret_cast<const f32x4*>(bq + o0);
                unsigned w = pk4fp8((qacc[lb][q * 4 + 0] + bq4[0]) * 0.0625f,
                                    (qacc[lb][q * 4 + 1] + bq4[1]) * 0.0625f,
                                    (qacc[lb][q * 4 + 2] + bq4[2]) * 0.0625f,
                                    (qacc[lb][q * 4 + 3] + bq4[3]) * 0.0625f);
                int pos0 = bs34(o0);
                *reinterpret_cast<unsigned*>(qt + l * 256 + (pos0 ^ lsw)) = w;
            }
        }
        __syncthreads();
        const int qrow = qg * 32 + l31;
        const int qswz = (qrow & 7) << 4;
#pragma unroll
        for (int ks2 = 0; ks2 < 8; ++ks2) {
            u32x4 v = *reinterpret_cast<const u32x4*>(
                qt + qrow * 256 + ((ks2 * 32 + hi * 16) ^ qswz));
            u32x2 lo; lo[0] = v[0]; lo[1] = v[1];
            u32x2 hi2; hi2[0] = v[2]; hi2[1] = v[3];
            qf2[2 * ks2]     = __builtin_bit_cast(long, lo);
            qf2[2 * ks2 + 1] = __builtin_bit_cast(long, hi2);
        }
        __syncthreads();   // qf2 everywhere; K/V regions may be overwritten
    }

    // ======== main flash loop ========
    const char* Kg = (const char*)(kb8 + (size_t)b * M_ * C_);   // fp8 [M][256B]
    int ksrc[2];
#pragma unroll
    for (int i = 0; i < 2; ++i) {
        int chunk = i * 8 + wave;
        int mr = chunk * 4 + (lane >> 4);
        ksrc[i] = mr * 256 + (((lane & 15) * 16) ^ ((mr & 7) << 4));
    }
    // V reg-stage geometry: fp8 [c][72B] rows, each lane stages 32B of one row
    const int vrow = wave * 32 + (lane >> 1);      // 0..255
    const int vhalf = (lane & 1) * 32;             // 0 / 32
    const char* VgRow = (const char*)(vb8 + (size_t)b * C_ * M_ + (size_t)vrow * M_);
    const int vdoff = vrow * 72 + vhalf;

    // prologue staging: K tile0 DMA + V tile0 reg-stage
#pragma unroll
    for (int i = 0; i < 2; ++i)
        gload_lds16(Kg + ksrc[i], Kbase_l + (i * 8 + wave) * 1024);
    {
        u32x4 s0 = *reinterpret_cast<const u32x4*>(VgRow + vhalf);
        u32x4 s1 = *reinterpret_cast<const u32x4*>(VgRow + vhalf + 16);
        char* vd = smem + 32768 + vdoff;
        u32x2 w;
        w[0] = s0[0]; w[1] = s0[1]; *reinterpret_cast<u32x2*>(vd) = w;
        w[0] = s0[2]; w[1] = s0[3]; *reinterpret_cast<u32x2*>(vd + 8) = w;
        w[0] = s1[0]; w[1] = s1[1]; *reinterpret_cast<u32x2*>(vd + 16) = w;
        w[0] = s1[2]; w[1] = s1[3]; *reinterpret_cast<u32x2*>(vd + 24) = w;
    }

    f32x16 acc[8];
#pragma unroll
    for (int cb = 0; cb < 8; ++cb)
#pragma unroll
        for (int r = 0; r < 16; ++r) acc[cb][r] = 0.f;
    float m_run = -INFINITY, l_run = 0.f;

    asm volatile("s_waitcnt vmcnt(0) lgkmcnt(0)" ::: "memory");
    __builtin_amdgcn_s_barrier();
    asm volatile("" ::: "memory");

    for (int kt = 0; kt < NT; ++kt) {
        const int cur = kt & 1;
        u32x4 vstg0, vstg1;
        if (kt + 1 < NT) {
            const char* Kn = Kg + (size_t)(kt + 1) * 16384;
            char* Kd = Kbase_l + (cur ^ 1) * 16384;
#pragma unroll
            for (int i = 0; i < 2; ++i)
                gload_lds16(Kn + ksrc[i], Kd + (i * 8 + wave) * 1024);
            const char* src = VgRow + (size_t)(kt + 1) * 64 + vhalf;
            vstg0 = *reinterpret_cast<const u32x4*>(src);
            vstg1 = *reinterpret_cast<const u32x4*>(src + 16);
        }

        // ---- S = K' x Q (fp8): 8 reads x 2 MFMA ----
        const char* Kc = Kbase_l + cur * 16384;
        const int mrow = mh * 32 + l31;
        const int msw = (mrow & 7) << 4;
        const int moff = mrow * 256;
        f32x16 s;
#pragma unroll
        for (int r = 0; r < 16; ++r) s[r] = 0.f;
        __builtin_amdgcn_s_setprio(1);
#pragma unroll
        for (int ks2 = 0; ks2 < 8; ++ks2) {
            u32x4 kv = *reinterpret_cast<const u32x4*>(
                Kc + moff + ((ks2 * 32 + hi * 16) ^ msw));
            u32x2 lo; lo[0] = kv[0]; lo[1] = kv[1];
            u32x2 hi2; hi2[0] = kv[2]; hi2[1] = kv[3];
            long a_e = __builtin_bit_cast(long, lo);
            long a_o = __builtin_bit_cast(long, hi2);
            s = __builtin_amdgcn_mfma_f32_32x32x16_fp8_fp8(a_e, qf2[2 * ks2], s, 0, 0, 0);
            s = __builtin_amdgcn_mfma_f32_32x32x16_fp8_fp8(a_o, qf2[2 * ks2 + 1], s, 0, 0, 0);
        }
        __builtin_amdgcn_s_setprio(0);

        // ---- online softmax; defer-max THR=6 so P <= e^6 = 403 < 448 (e4m3 max) ----
        float pv[16];
        float tm = -INFINITY;
#pragma unroll
        for (int r = 0; r < 16; ++r) {
            pv[r] = s[r];
            tm = fmaxf(tm, s[r]);
        }
        tm = fmaxf(tm, __shfl_xor(tm, 32));
        if (!__all(tm - m_run <= 6.0f)) {
            float m_new = fmaxf(m_run, tm);
            float corr = __expf(m_run - m_new);
#pragma unroll
            for (int cb = 0; cb < 8; ++cb)
#pragma unroll
                for (int r = 0; r < 16; ++r) acc[cb][r] *= corr;
            l_run *= corr;
            m_run = m_new;
        }
        float rs = 0.f;
#pragma unroll
        for (int i = 0; i < 16; ++i) { pv[i] = __expf(pv[i] - m_run); rs += pv[i]; }
        l_run += rs + __shfl_xor(rs, 32);

        // ---- build P fp8 B-frags: 4 cvt_pk + 2 permlane swaps ----
        long pf0, pf1;
        {
            unsigned U0 = pk4fp8(pv[0], pv[1], pv[2], pv[3]);     // rows 0-3 (+4hi)
            unsigned U1 = pk4fp8(pv[4], pv[5], pv[6], pv[7]);     // rows 8-11
            unsigned U2 = pk4fp8(pv[8], pv[9], pv[10], pv[11]);   // rows 16-19
            unsigned U3 = pk4fp8(pv[12], pv[13], pv[14], pv[15]); // rows 24-27
            pl32swapu(U0, U1);
            pl32swapu(U2, U3);
            u32x2 p0; p0[0] = U0; p0[1] = U1;
            u32x2 p1; p1[0] = U2; p1[1] = U3;
            pf0 = __builtin_bit_cast(long, p0);
            pf1 = __builtin_bit_cast(long, p1);
        }

        // ---- PV (fp8): A = V[c][m] b64 reads, B = P regs ----
        const char* Vc = smem + 32768 + cur * 18432;
        __builtin_amdgcn_s_setprio(1);
#pragma unroll
        for (int ks2 = 0; ks2 < 2; ++ks2) {
            int mo = mh * 32 + ks2 * 16 + hi * 8;
            long pf = ks2 ? pf1 : pf0;
#pragma unroll
            for (int cb = 0; cb < 8; ++cb) {
                int c = cb * 32 + l31;
                long av = *reinterpret_cast<const long*>(Vc + c * 72 + mo);
                acc[cb] = __builtin_amdgcn_mfma_f32_32x32x16_fp8_fp8(av, pf, acc[cb], 0, 0, 0);
            }
        }
        __builtin_amdgcn_s_setprio(0);

        // ---- drain loads; write V[kt+1]; publish; barrier ----
        asm volatile("s_waitcnt vmcnt(0) lgkmcnt(0)" ::: "memory");
        if (kt + 1 < NT) {
            char* vd = smem + 32768 + (cur ^ 1) * 18432 + vdoff;
            u32x2 w;
            w[0] = vstg0[0]; w[1] = vstg0[1]; *reinterpret_cast<u32x2*>(vd) = w;
            w[0] = vstg0[2]; w[1] = vstg0[3]; *reinterpret_cast<u32x2*>(vd + 8) = w;
            w[0] = vstg1[0]; w[1] = vstg1[1]; *reinterpret_cast<u32x2*>(vd + 16) = w;
            w[0] = vstg1[2]; w[1] = vstg1[3]; *reinterpret_cast<u32x2*>(vd + 24) = w;
        }
        asm volatile("s_waitcnt lgkmcnt(0)" ::: "memory");
        __builtin_amdgcn_s_barrier();
        asm volatile("" ::: "memory");
    }

    // ---- split-K merge between wave pairs (qg, 0) <-> (qg, 1) ----
    f32x2* mlb = (f32x2*)(smem + 131072);
    f32x2 myml; myml[0] = m_run; myml[1] = l_run;
    mlb[wave * 64 + lane] = myml;
    __syncthreads();
    f32x2 pml = mlb[(wave ^ 4) * 64 + lane];
    float m_star = fmaxf(m_run, pml[0]);
    float f_self = __expf(m_run - m_star);
    float f_peer = __expf(pml[0] - m_star);
    float l_tot = l_run * f_self + pml[1] * f_peer;
#pragma unroll
    for (int cb = 0; cb < 8; ++cb)
#pragma unroll
        for (int r = 0; r < 16; ++r) acc[cb][r] *= f_self;

    char* xbuf = smem;
    const int myoff = (qg * 2 + mh) * 16384;
    __syncthreads();
#pragma unroll
    for (int cbl = 0; cbl < 4; ++cbl)
#pragma unroll
        for (int q = 0; q < 4; ++q) {
            f32x4 chunk;
#pragma unroll
            for (int j = 0; j < 4; ++j) {
                float a_lo = acc[cbl][q * 4 + j];
                float a_hi = acc[4 + cbl][q * 4 + j];
                chunk[j] = mh ? a_lo : a_hi;
            }
            *reinterpret_cast<f32x4*>(xbuf + myoff + (cbl * 4 + q) * 1024 + lane * 16) = chunk;
        }
    __syncthreads();

    const int poff = (qg * 2 + (1 - mh)) * 16384;
    float gt = tanhf(gate[0]);
    float scale = gt / l_tot;
    const float* xp = x + (size_t)b * C_ * L_;
    float* op = out + (size_t)b * C_ * L_;
    int lcol = l0w + l31;
    const int cbase = mh * 4;
#pragma unroll
    for (int cbl = 0; cbl < 4; ++cbl) {
#pragma unroll
        for (int q = 0; q < 4; ++q) {
            f32x4 pc = *reinterpret_cast<const f32x4*>(xbuf + poff + (cbl * 4 + q) * 1024 + lane * 16);
#pragma unroll
            for (int j = 0; j < 4; ++j) {
                float a_lo = acc[cbl][q * 4 + j];
                float a_hi = acc[4 + cbl][q * 4 + j];
                float mine = mh ? a_hi : a_lo;
                int c = (cbase + cbl) * 32 + j + 8 * q + 4 * hi;
                size_t idx = (size_t)c * L_ + lcol;
                op[idx] = (mine + pc[j]) * scale + xp[idx];
            }
        }
    }
}

extern "C" void kernel_launch(void* const* d_in, const int* in_sizes, int n_in,
                              void* d_out, int out_size, void* d_ws, size_t ws_size,
                              hipStream_t stream) {
    const float* x    = (const float*)d_in[0];
    const float* Wq   = (const float*)d_in[1];
    const float* bq   = (const float*)d_in[2];
    const float* Wk   = (const float*)d_in[3];
    const float* bk   = (const float*)d_in[4];
    const float* Wv   = (const float*)d_in[5];
    const float* bv   = (const float*)d_in[6];
    const float* gate = (const float*)d_in[7];
    float* out = (float*)d_out;

    char* ws = (char*)d_ws;
    const size_t szK8 = (size_t)B_ * M_ * C_;        // 4194304 (fp8)
    const size_t szV8 = (size_t)B_ * M_ * C_;        // 4194304 (fp8)
    const size_t szW  = (size_t)C_ * C_ * 2;         // 131072
    unsigned char* kbuf8 = (unsigned char*)(ws);
    unsigned char* vbuf8 = (unsigned char*)(ws + szK8);
    bf16_t* Wqb  = (bf16_t*)(ws + szK8 + szV8);
    bf16_t* Wkb  = (bf16_t*)(ws + szK8 + szV8 + szW);
    bf16_t* Wvb  = (bf16_t*)(ws + szK8 + szV8 + 2 * szW);

    conv_w_kernel<<<768, 256, 0, stream>>>(Wq, Wk, Wv, Wqb, Wkb, Wvb);
    kv_proj_kernel<<<512, 256, 0, stream>>>(x, Wkb, bk, Wvb, bv, kbuf8, vbuf8);
    attn_kernel<<<256, 512, 0, stream>>>(Wqb, bq, kbuf8, vbuf8, x, gate, out);
}

// Round 16
// 98.285 us; speedup vs baseline: 1.6957x; 1.0443x over previous
//
#include <hip/hip_runtime.h>
#include <hip/hip_bf16.h>

typedef __bf16 bf16_t;
typedef __bf16 bf16x8 __attribute__((ext_vector_type(8)));
typedef float  f32x2  __attribute__((ext_vector_type(2)));
typedef float  f32x4  __attribute__((ext_vector_type(4)));
typedef float  f32x16 __attribute__((ext_vector_type(16)));
typedef unsigned u32x2 __attribute__((ext_vector_type(2)));
typedef unsigned u32x4 __attribute__((ext_vector_type(4)));
typedef int    i32x8  __attribute__((ext_vector_type(8)));

#define B_ 8
#define C_ 256
#define L_ 4096
#define M_ 2048
#define INV_SQRT2f 0.70710678118654752440f

typedef __attribute__((address_space(3))) void as3_void;
typedef __attribute__((address_space(1))) const void as1_cvoid;

__device__ __forceinline__ void gload_lds16(const void* g, void* l) {
    __builtin_amdgcn_global_load_lds((as1_cvoid*)g, (as3_void*)l, 16, 0, 0);
}

__device__ __forceinline__ const bf16x8* ldg8(const bf16_t* p) {
    return reinterpret_cast<const bf16x8*>(p);
}

__device__ __forceinline__ unsigned packbf(float a, float b) {
    unsigned short ua = __builtin_bit_cast(unsigned short, (bf16_t)a);
    unsigned short ub = __builtin_bit_cast(unsigned short, (bf16_t)b);
    return (unsigned)ua | ((unsigned)ub << 16);
}

// v_permlane32_swap_b32 — ONLY on operands with DISTINCT values.
__device__ __forceinline__ void pl32swapu(unsigned &a, unsigned &b) {
    asm("v_permlane32_swap_b32 %0, %1" : "+v"(a), "+v"(b));
}

// swap bits 3 and 4 (sigma c-permutation for K/Q; involution)
__device__ __forceinline__ int bs34(int v) {
    return (v & ~0x18) | ((v & 8) << 1) | ((v & 16) >> 1);
}

// pack 4 f32 -> 4 fp8 e4m3 bytes (ascending byte order)
__device__ __forceinline__ unsigned pk4fp8(float a, float b, float c, float d) {
    int u = __builtin_amdgcn_cvt_pk_fp8_f32(a, b, 0, false);
    u = __builtin_amdgcn_cvt_pk_fp8_f32(c, d, u, true);
    return (unsigned)u;
}

// ---------------- kernel 0: weight conversion f32 -> bf16 (once) ----------------
__global__ __launch_bounds__(256) void conv_w_kernel(
    const float* __restrict__ Wq, const float* __restrict__ Wk, const float* __restrict__ Wv,
    bf16_t* __restrict__ Wqb, bf16_t* __restrict__ Wkb, bf16_t* __restrict__ Wvb) {
    int idx = blockIdx.x * 256 + threadIdx.x;
    int which = idx >> 16;
    int off = idx & 65535;
    const float* src = (which == 0) ? Wq : ((which == 1) ? Wk : Wv);
    bf16_t* dst = (which == 0) ? Wqb : ((which == 1) ? Wkb : Wvb);
    dst[off] = (bf16_t)src[off];
}

// ================= kernel A: fused Haar + K-proj(fp8) + V-proj(fp8) =================
__global__ __launch_bounds__(256, 2) void kv_proj_kernel(
    const float* __restrict__ x, const bf16_t* __restrict__ Wk, const float* __restrict__ bk,
    const bf16_t* __restrict__ Wv, const float* __restrict__ bv,
    unsigned char* __restrict__ kb8, unsigned char* __restrict__ vb8) {
    __shared__ __align__(16) char smem[16384 + 33280];
    char* xh = smem;                           // [32][512B] swizzled bf16
    float* tile = (float*)(smem + 16384);      // f32 [64][130]

    const int t = threadIdx.x;
    const int wave = t >> 6, lane = t & 63;
    const int l31 = lane & 31, hi = lane >> 5;
    const int bid = blockIdx.x;
    const int b = bid & 7;
    const int mt = bid >> 3;        // 0..63
    const int m0 = mt * 32;

    // ---- phase 1: build xh (4 c-chunks of 64), reg-staged pipeline ----
    const int c2 = (t & 31) * 2;
    const int mg = t >> 5;
    const int lrow = t >> 5;
    const int lcp  = t & 31;
    f32x2 stage[8];
    {
        const float* xs = x + ((size_t)(b * C_) * L_) + 2 * m0;
#pragma unroll
        for (int j = 0; j < 8; ++j)
            stage[j] = *reinterpret_cast<const f32x2*>(xs + (size_t)(lrow + 8 * j) * L_ + lcp * 2);
    }
    for (int cc = 0; cc < 4; ++cc) {
        if (cc) __syncthreads();
#pragma unroll
        for (int j = 0; j < 8; ++j)
            *reinterpret_cast<f32x2*>(tile + (lrow + 8 * j) * 130 + lcp * 2) = stage[j];
        __syncthreads();
        if (cc < 3) {
            const float* xs = x + ((size_t)(b * C_ + (cc + 1) * 64) * L_) + 2 * m0;
#pragma unroll
            for (int j = 0; j < 8; ++j)
                stage[j] = *reinterpret_cast<const f32x2*>(xs + (size_t)(lrow + 8 * j) * L_ + lcp * 2);
        }
#pragma unroll
        for (int i = 0; i < 4; ++i) {
            int m = mg * 4 + i;
            f32x2 pa = *reinterpret_cast<const f32x2*>(tile + c2 * 130 + 2 * m);
            f32x2 pb = *reinterpret_cast<const f32x2*>(tile + (c2 + 1) * 130 + 2 * m);
            float va  = (pa[0] - pa[1]) * INV_SQRT2f;
            float vb2 = (pb[0] - pb[1]) * INV_SQRT2f;
            int byte = m * 512 + ((((cc * 64 + c2) * 2)) ^ ((m & 7) << 4));
            *reinterpret_cast<unsigned*>(xh + byte) = packbf(va, vb2);
        }
    }
    __syncthreads();

    // ---- phase 2: merged K-proj + V-proj (shared xh reads, bf16 weights) ----
    const int oq = wave;
    f32x16 kacc[2], vacc[2];
#pragma unroll
    for (int ob = 0; ob < 2; ++ob) {
        float bko = bk[(oq * 2 + ob) * 32 + l31];
#pragma unroll
        for (int r = 0; r < 16; ++r) { kacc[ob][r] = bko; vacc[ob][r] = 0.f; }
    }
    const int s0 = (l31 & 7) << 4;
#pragma unroll
    for (int ks = 0; ks < 16; ++ks) {
        int cb = (ks * 16 + hi * 8) * 2;
        bf16x8 xv = *reinterpret_cast<const bf16x8*>(xh + l31 * 512 + (cb ^ s0));
#pragma unroll
        for (int ob = 0; ob < 2; ++ob) {
            int o = (oq * 2 + ob) * 32 + l31;
            bf16x8 bw = *ldg8(Wk + (size_t)o * C_ + ks * 16 + hi * 8);
            kacc[ob] = __builtin_amdgcn_mfma_f32_32x32x16_bf16(xv, bw, kacc[ob], 0, 0, 0);
            bf16x8 aw = *ldg8(Wv + (size_t)o * C_ + ks * 16 + hi * 8);
            vacc[ob] = __builtin_amdgcn_mfma_f32_32x32x16_bf16(aw, xv, vacc[ob], 0, 0, 0);
        }
    }
    // K out: fp8, sigma-permuted channels. V out: fp8 [C][M], plain.
    unsigned char* kout8 = kb8 + (size_t)b * M_ * C_;
    unsigned char* vout8 = vb8 + (size_t)b * C_ * M_;
#pragma unroll
    for (int ob = 0; ob < 2; ++ob) {
        int o = (oq * 2 + ob) * 32 + l31;
        int g = bs34(o);
#pragma unroll
        for (int r = 0; r < 16; ++r) {
            int mloc = (r & 3) + 8 * (r >> 2) + 4 * hi;
            unsigned p = (unsigned)__builtin_amdgcn_cvt_pk_fp8_f32(kacc[ob][r], kacc[ob][r], 0, false);
            kout8[(size_t)(m0 + mloc) * C_ + g] = (unsigned char)(p & 0xFF);
        }
#pragma unroll
        for (int r = 0; r < 16; ++r) {
            int ov = (oq * 2 + ob) * 32 + (r & 3) + 8 * (r >> 2) + 4 * hi;
            float val = vacc[ob][r] + bv[ov];
            unsigned p = (unsigned)__builtin_amdgcn_cvt_pk_fp8_f32(val, val, 0, false);
            vout8[(size_t)ov * M_ + m0 + l31] = (unsigned char)(p & 0xFF);
        }
    }
}

// ================= kernel B: attention, fp8 S (MX K=64) and fp8 PV =================
#define KT 64
#define NT (M_ / KT)   // 32

// LDS map (main loop): K fp8 dbuf [0,32K) | V fp8 [c][72B] dbuf [32768, 69632)
// prologue: qt @0 (32K fp8), xt @32768 (64K), tile @98304; mlb @131072.
__global__ __launch_bounds__(512, 1) void attn_kernel(
    const bf16_t* __restrict__ Wq, const float* __restrict__ bq,
    const unsigned char* __restrict__ kb8, const unsigned char* __restrict__ vb8,
    const float* __restrict__ x, const float* __restrict__ gate, float* __restrict__ out) {
    __shared__ __align__(16) char smem[135168];
    char* Kbase_l = smem;                   // 32KB K fp8 dbuf / qt
    float* tile   = (float*)(smem + 98304); // prologue scratch

    const int t = threadIdx.x;
    const int wave = t >> 6, lane = t & 63;
    const int qg = wave & 3, mh = wave >> 2;
    const int l31 = lane & 31, hi = lane >> 5;
    const int bid = blockIdx.x;
    const int b = bid & 7;
    const int lt = bid >> 3;
    const int l0w = lt * 128 + qg * 32;

    i32x8 qfr[4];   // fp8 Q B-frags for MX K=64 S-MFMA (8 regs each)

    // ======== Q-projection prologue (bf16 GEMM, fp8 pack; scale 2^-4 folded) ========
    {
        char* xt = smem + 32768;         // [128][512B] bf16 swizzled
        const int cp2 = (t & 31) * 2;
        const int lg = t >> 5;
        const int lrow = t >> 6;
        const int lcp  = t & 63;
        f32x2 stage[8];
        {
            const float* xs = x + ((size_t)(b * C_) * L_) + lt * 128;
#pragma unroll
            for (int j = 0; j < 8; ++j)
                stage[j] = *reinterpret_cast<const f32x2*>(xs + (size_t)(lrow + 8 * j) * L_ + lcp * 2);
        }
        for (int cc = 0; cc < 4; ++cc) {
            if (cc) __syncthreads();
#pragma unroll
            for (int j = 0; j < 8; ++j)
                *reinterpret_cast<f32x2*>(tile + (lrow + 8 * j) * 130 + lcp * 2) = stage[j];
            __syncthreads();
            if (cc < 3) {
                const float* xs = x + ((size_t)(b * C_ + (cc + 1) * 64) * L_) + lt * 128;
#pragma unroll
                for (int j = 0; j < 8; ++j)
                    stage[j] = *reinterpret_cast<const f32x2*>(xs + (size_t)(lrow + 8 * j) * L_ + lcp * 2);
            }
#pragma unroll
            for (int i = 0; i < 8; ++i) {
                int l = lg * 8 + i;
                float va  = tile[cp2 * 130 + l];
                float vb2 = tile[(cp2 + 1) * 130 + l];
                int byte = l * 512 + ((((cc * 64 + cp2) * 2)) ^ ((l & 7) << 4));
                *reinterpret_cast<unsigned*>(xt + byte) = packbf(va, vb2);
            }
        }
        __syncthreads();

        const int ow = wave * 32;
        f32x16 qacc[4];
#pragma unroll
        for (int lb = 0; lb < 4; ++lb)
#pragma unroll
            for (int r = 0; r < 16; ++r) qacc[lb][r] = 0.f;
#pragma unroll
        for (int ks = 0; ks < 16; ++ks) {
            bf16x8 aw = *ldg8(Wq + (size_t)(ow + l31) * C_ + ks * 16 + hi * 8);
#pragma unroll
            for (int lb = 0; lb < 4; ++lb) {
                int lrow2 = lb * 32 + l31;
                bf16x8 bx = *reinterpret_cast<const bf16x8*>(
                    xt + lrow2 * 512 + (((ks * 16 + hi * 8) * 2) ^ ((lrow2 & 7) << 4)));
                qacc[lb] = __builtin_amdgcn_mfma_f32_32x32x16_bf16(aw, bx, qacc[lb], 0, 0, 0);
            }
        }
        // qt: fp8 [128][256B], sigma-permuted c, swz=((l&7)<<4)
        char* qt = Kbase_l;
#pragma unroll
        for (int lb = 0; lb < 4; ++lb) {
            int l = lb * 32 + l31;
            int lsw = (l & 7) << 4;
#pragma unroll
            for (int q = 0; q < 4; ++q) {
                int o0 = ow + 4 * hi + 8 * q;
                f32x4 bq4 = *reinterpret_cast<const f32x4*>(bq + o0);
                unsigned w = pk4fp8((qacc[lb][q * 4 + 0] + bq4[0]) * 0.0625f,
                                    (qacc[lb][q * 4 + 1] + bq4[1]) * 0.0625f,
                                    (qacc[lb][q * 4 + 2] + bq4[2]) * 0.0625f,
                                    (qacc[lb][q * 4 + 3] + bq4[3]) * 0.0625f);
                int pos0 = bs34(o0);
                *reinterpret_cast<unsigned*>(qt + l * 256 + (pos0 ^ lsw)) = w;
            }
        }
        __syncthreads();
        const int qrow = qg * 32 + l31;
        const int qswz = (qrow & 7) << 4;
#pragma unroll
        for (int i = 0; i < 4; ++i) {
            u32x4 v0 = *reinterpret_cast<const u32x4*>(
                qt + qrow * 256 + (((2 * i) * 32 + hi * 16) ^ qswz));
            u32x4 v1 = *reinterpret_cast<const u32x4*>(
                qt + qrow * 256 + (((2 * i + 1) * 32 + hi * 16) ^ qswz));
            i32x8 q;
            q[0] = (int)v0[0]; q[1] = (int)v0[1]; q[2] = (int)v0[2]; q[3] = (int)v0[3];
            q[4] = (int)v1[0]; q[5] = (int)v1[1]; q[6] = (int)v1[2]; q[7] = (int)v1[3];
            qfr[i] = q;
        }
        __syncthreads();   // qfr everywhere; K/V regions may be overwritten
    }

    // ======== main flash loop ========
    const char* Kg = (const char*)(kb8 + (size_t)b * M_ * C_);   // fp8 [M][256B]
    int ksrc[2];
#pragma unroll
    for (int i = 0; i < 2; ++i) {
        int chunk = i * 8 + wave;
        int mr = chunk * 4 + (lane >> 4);
        ksrc[i] = mr * 256 + (((lane & 15) * 16) ^ ((mr & 7) << 4));
    }
    // V reg-stage geometry: fp8 [c][72B] rows, each lane stages 32B of one row
    const int vrow = wave * 32 + (lane >> 1);      // 0..255
    const int vhalf = (lane & 1) * 32;             // 0 / 32
    const char* VgRow = (const char*)(vb8 + (size_t)b * C_ * M_ + (size_t)vrow * M_);
    const int vdoff = vrow * 72 + vhalf;

    // prologue staging: K tile0 DMA + V tile0 reg-stage
#pragma unroll
    for (int i = 0; i < 2; ++i)
        gload_lds16(Kg + ksrc[i], Kbase_l + (i * 8 + wave) * 1024);
    {
        u32x4 s0 = *reinterpret_cast<const u32x4*>(VgRow + vhalf);
        u32x4 s1 = *reinterpret_cast<const u32x4*>(VgRow + vhalf + 16);
        char* vd = smem + 32768 + vdoff;
        u32x2 w;
        w[0] = s0[0]; w[1] = s0[1]; *reinterpret_cast<u32x2*>(vd) = w;
        w[0] = s0[2]; w[1] = s0[3]; *reinterpret_cast<u32x2*>(vd + 8) = w;
        w[0] = s1[0]; w[1] = s1[1]; *reinterpret_cast<u32x2*>(vd + 16) = w;
        w[0] = s1[2]; w[1] = s1[3]; *reinterpret_cast<u32x2*>(vd + 24) = w;
    }

    f32x16 acc[8];
#pragma unroll
    for (int cb = 0; cb < 8; ++cb)
#pragma unroll
        for (int r = 0; r < 16; ++r) acc[cb][r] = 0.f;
    float m_run = -INFINITY, l_run = 0.f;

    asm volatile("s_waitcnt vmcnt(0) lgkmcnt(0)" ::: "memory");
    __builtin_amdgcn_s_barrier();
    asm volatile("" ::: "memory");

    for (int kt = 0; kt < NT; ++kt) {
        const int cur = kt & 1;
        u32x4 vstg0, vstg1;
        if (kt + 1 < NT) {
            const char* Kn = Kg + (size_t)(kt + 1) * 16384;
            char* Kd = Kbase_l + (cur ^ 1) * 16384;
#pragma unroll
            for (int i = 0; i < 2; ++i)
                gload_lds16(Kn + ksrc[i], Kd + (i * 8 + wave) * 1024);
            const char* src = VgRow + (size_t)(kt + 1) * 64 + vhalf;
            vstg0 = *reinterpret_cast<const u32x4*>(src);
            vstg1 = *reinterpret_cast<const u32x4*>(src + 16);
        }

        // ---- S = K' x Q (fp8, MX K=64, scale=1): 8 b128 reads -> 4 MFMA ----
        const char* Kc = Kbase_l + cur * 16384;
        const int mrow = mh * 32 + l31;
        const int msw = (mrow & 7) << 4;
        const int moff = mrow * 256;
        f32x16 s;
#pragma unroll
        for (int r = 0; r < 16; ++r) s[r] = 0.f;
        __builtin_amdgcn_s_setprio(1);
#pragma unroll
        for (int i = 0; i < 4; ++i) {
            u32x4 k0 = *reinterpret_cast<const u32x4*>(
                Kc + moff + (((2 * i) * 32 + hi * 16) ^ msw));
            u32x4 k1 = *reinterpret_cast<const u32x4*>(
                Kc + moff + (((2 * i + 1) * 32 + hi * 16) ^ msw));
            i32x8 a;
            a[0] = (int)k0[0]; a[1] = (int)k0[1]; a[2] = (int)k0[2]; a[3] = (int)k0[3];
            a[4] = (int)k1[0]; a[5] = (int)k1[1]; a[6] = (int)k1[2]; a[7] = (int)k1[3];
            s = __builtin_amdgcn_mfma_scale_f32_32x32x64_f8f6f4(
                    a, qfr[i], s, 0, 0, 0, 0x7F7F7F7F, 0, 0x7F7F7F7F);
        }
        __builtin_amdgcn_s_setprio(0);

        // ---- online softmax; defer-max THR=6 so P <= e^6 = 403 < 448 (e4m3 max) ----
        float pv[16];
        float tm = -INFINITY;
#pragma unroll
        for (int r = 0; r < 16; ++r) {
            pv[r] = s[r];
            tm = fmaxf(tm, s[r]);
        }
        tm = fmaxf(tm, __shfl_xor(tm, 32));
        if (!__all(tm - m_run <= 6.0f)) {
            float m_new = fmaxf(m_run, tm);
            float corr = __expf(m_run - m_new);
#pragma unroll
            for (int cb = 0; cb < 8; ++cb)
#pragma unroll
                for (int r = 0; r < 16; ++r) acc[cb][r] *= corr;
            l_run *= corr;
            m_run = m_new;
        }
        float rs = 0.f;
#pragma unroll
        for (int i = 0; i < 16; ++i) { pv[i] = __expf(pv[i] - m_run); rs += pv[i]; }
        l_run += rs + __shfl_xor(rs, 32);

        // ---- build P fp8 B-frags: 4 cvt_pk + 2 permlane swaps ----
        long pf0, pf1;
        {
            unsigned U0 = pk4fp8(pv[0], pv[1], pv[2], pv[3]);     // rows 0-3 (+4hi)
            unsigned U1 = pk4fp8(pv[4], pv[5], pv[6], pv[7]);     // rows 8-11
            unsigned U2 = pk4fp8(pv[8], pv[9], pv[10], pv[11]);   // rows 16-19
            unsigned U3 = pk4fp8(pv[12], pv[13], pv[14], pv[15]); // rows 24-27
            pl32swapu(U0, U1);
            pl32swapu(U2, U3);
            u32x2 p0; p0[0] = U0; p0[1] = U1;
            u32x2 p1; p1[0] = U2; p1[1] = U3;
            pf0 = __builtin_bit_cast(long, p0);
            pf1 = __builtin_bit_cast(long, p1);
        }

        // ---- PV (fp8): A = V[c][m] b64 reads, B = P regs ----
        const char* Vc = smem + 32768 + cur * 18432;
        __builtin_amdgcn_s_setprio(1);
#pragma unroll
        for (int ks2 = 0; ks2 < 2; ++ks2) {
            int mo = mh * 32 + ks2 * 16 + hi * 8;
            long pf = ks2 ? pf1 : pf0;
#pragma unroll
            for (int cb = 0; cb < 8; ++cb) {
                int c = cb * 32 + l31;
                long av = *reinterpret_cast<const long*>(Vc + c * 72 + mo);
                acc[cb] = __builtin_amdgcn_mfma_f32_32x32x16_fp8_fp8(av, pf, acc[cb], 0, 0, 0);
            }
        }
        __builtin_amdgcn_s_setprio(0);

        // ---- drain loads; write V[kt+1]; publish; barrier ----
        asm volatile("s_waitcnt vmcnt(0) lgkmcnt(0)" ::: "memory");
        if (kt + 1 < NT) {
            char* vd = smem + 32768 + (cur ^ 1) * 18432 + vdoff;
            u32x2 w;
            w[0] = vstg0[0]; w[1] = vstg0[1]; *reinterpret_cast<u32x2*>(vd) = w;
            w[0] = vstg0[2]; w[1] = vstg0[3]; *reinterpret_cast<u32x2*>(vd + 8) = w;
            w[0] = vstg1[0]; w[1] = vstg1[1]; *reinterpret_cast<u32x2*>(vd + 16) = w;
            w[0] = vstg1[2]; w[1] = vstg1[3]; *reinterpret_cast<u32x2*>(vd + 24) = w;
        }
        asm volatile("s_waitcnt lgkmcnt(0)" ::: "memory");
        __builtin_amdgcn_s_barrier();
        asm volatile("" ::: "memory");
    }

    // ---- split-K merge between wave pairs (qg, 0) <-> (qg, 1) ----
    f32x2* mlb = (f32x2*)(smem + 131072);
    f32x2 myml; myml[0] = m_run; myml[1] = l_run;
    mlb[wave * 64 + lane] = myml;
    __syncthreads();
    f32x2 pml = mlb[(wave ^ 4) * 64 + lane];
    float m_star = fmaxf(m_run, pml[0]);
    float f_self = __expf(m_run - m_star);
    float f_peer = __expf(pml[0] - m_star);
    float l_tot = l_run * f_self + pml[1] * f_peer;
#pragma unroll
    for (int cb = 0; cb < 8; ++cb)
#pragma unroll
        for (int r = 0; r < 16; ++r) acc[cb][r] *= f_self;

    char* xbuf = smem;
    const int myoff = (qg * 2 + mh) * 16384;
    __syncthreads();
#pragma unroll
    for (int cbl = 0; cbl < 4; ++cbl)
#pragma unroll
        for (int q = 0; q < 4; ++q) {
            f32x4 chunk;
#pragma unroll
            for (int j = 0; j < 4; ++j) {
                float a_lo = acc[cbl][q * 4 + j];
                float a_hi = acc[4 + cbl][q * 4 + j];
                chunk[j] = mh ? a_lo : a_hi;
            }
            *reinterpret_cast<f32x4*>(xbuf + myoff + (cbl * 4 + q) * 1024 + lane * 16) = chunk;
        }
    __syncthreads();

    const int poff = (qg * 2 + (1 - mh)) * 16384;
    float gt = tanhf(gate[0]);
    float scale = gt / l_tot;
    const float* xp = x + (size_t)b * C_ * L_;
    float* op = out + (size_t)b * C_ * L_;
    int lcol = l0w + l31;
    const int cbase = mh * 4;
#pragma unroll
    for (int cbl = 0; cbl < 4; ++cbl) {
#pragma unroll
        for (int q = 0; q < 4; ++q) {
            f32x4 pc = *reinterpret_cast<const f32x4*>(xbuf + poff + (cbl * 4 + q) * 1024 + lane * 16);
#pragma unroll
            for (int j = 0; j < 4; ++j) {
                float a_lo = acc[cbl][q * 4 + j];
                float a_hi = acc[4 + cbl][q * 4 + j];
                float mine = mh ? a_hi : a_lo;
                int c = (cbase + cbl) * 32 + j + 8 * q + 4 * hi;
                size_t idx = (size_t)c * L_ + lcol;
                op[idx] = (mine + pc[j]) * scale + xp[idx];
            }
        }
    }
}

extern "C" void kernel_launch(void* const* d_in, const int* in_sizes, int n_in,
                              void* d_out, int out_size, void* d_ws, size_t ws_size,
                              hipStream_t stream) {
    const float* x    = (const float*)d_in[0];
    const float* Wq   = (const float*)d_in[1];
    const float* bq   = (const float*)d_in[2];
    const float* Wk   = (const float*)d_in[3];
    const float* bk   = (const float*)d_in[4];
    const float* Wv   = (const float*)d_in[5];
    const float* bv   = (const float*)d_in[6];
    const float* gate = (const float*)d_in[7];
    float* out = (float*)d_out;

    char* ws = (char*)d_ws;
    const size_t szK8 = (size_t)B_ * M_ * C_;        // 4194304 (fp8)
    const size_t szV8 = (size_t)B_ * M_ * C_;        // 4194304 (fp8)
    const size_t szW  = (size_t)C_ * C_ * 2;         // 131072
    unsigned char* kbuf8 = (unsigned char*)(ws);
    unsigned char* vbuf8 = (unsigned char*)(ws + szK8);
    bf16_t* Wqb  = (bf16_t*)(ws + szK8 + szV8);
    bf16_t* Wkb  = (bf16_t*)(ws + szK8 + szV8 + szW);
    bf16_t* Wvb  = (bf16_t*)(ws + szK8 + szV8 + 2 * szW);

    conv_w_kernel<<<768, 256, 0, stream>>>(Wq, Wk, Wv, Wqb, Wkb, Wvb);
    kv_proj_kernel<<<512, 256, 0, stream>>>(x, Wkb, bk, Wvb, bv, kbuf8, vbuf8);
    attn_kernel<<<256, 512, 0, stream>>>(Wqb, bq, kbuf8, vbuf8, x, gate, out);
}